// Round 1
// baseline (842.147 us; speedup 1.0000x reference)
//
#include <hip/hip_runtime.h>
#include <math.h>

#define NE 8192  // num_users == num_items (fixed by reference setup_inputs)

// db3 analysis filters, reversed (cross-correlation of reversed filter == convolution)
__device__ __constant__ float LO_R[6] = {
    0.3326705529509569f, 0.8068915093133388f, 0.4598775021193313f,
    -0.13501102001039084f, -0.08544127388224149f, 0.035226291882100656f};
__device__ __constant__ float HI_R[6] = {
    0.035226291882100656f, 0.08544127388224149f, -0.13501102001039084f,
    -0.4598775021193313f, 0.8068915093133388f, -0.3326705529509569f};

// Block reduce: result valid on thread 0 only. Caller must __syncthreads()
// after consuming the result before red[] is reused.
__device__ __forceinline__ float blockReduceSum(float v, float* red) {
    #pragma unroll
    for (int off = 32; off > 0; off >>= 1) v += __shfl_down(v, off);
    int lane = threadIdx.x & 63, wid = threadIdx.x >> 6;
    if (lane == 0) red[wid] = v;
    __syncthreads();
    float r = 0.f;
    if (threadIdx.x == 0) {
        int nw = blockDim.x >> 6;
        for (int i = 0; i < nw; ++i) r += red[i];
    }
    return r;
}

__global__ void k_count(const int* __restrict__ ui, const int* __restrict__ ii,
                        const float* __restrict__ v, int nnz,
                        int* cntU, int* cntI, float* sumvI) {
    int idx = blockIdx.x * blockDim.x + threadIdx.x;
    int stride = gridDim.x * blockDim.x;
    for (int n = idx; n < nnz; n += stride) {
        atomicAdd(&cntU[ui[n]], 1);
        atomicAdd(&cntI[ii[n]], 1);
        atomicAdd(&sumvI[ii[n]], v[n]);
    }
}

__global__ void k_pop_raw(const int* __restrict__ cntI, const float* __restrict__ sumvI,
                          float* pop, float* normAcc) {
    __shared__ float red[4];
    int i = blockIdx.x * blockDim.x + threadIdx.x;
    float val = 0.f;
    if (i < NE) { val = log1pf((float)cntI[i]) * sumvI[i]; pop[i] = val; }
    float s = blockReduceSum(val * val, red);
    if (threadIdx.x == 0) atomicAdd(&normAcc[0], s);
}

__global__ void k_scale(float* arr, const float* __restrict__ normAcc, int slot) {
    int i = blockIdx.x * blockDim.x + threadIdx.x;
    float sc = 1.f / (sqrtf(normAcc[slot]) + 1e-8f);
    if (i < NE) arr[i] *= sc;
}

__global__ void k_act(const int* __restrict__ ui, const int* __restrict__ ii,
                      const float* __restrict__ v, int nnz,
                      const float* __restrict__ pop, float* act) {
    int idx = blockIdx.x * blockDim.x + threadIdx.x;
    int stride = gridDim.x * blockDim.x;
    for (int n = idx; n < nnz; n += stride) {
        atomicAdd(&act[ui[n]], v[n] / log1pf(pop[ii[n]] + 1e-8f));
    }
}

__global__ void k_sumsq(const float* __restrict__ arr, float* normAcc, int slot) {
    __shared__ float red[4];
    int i = blockIdx.x * blockDim.x + threadIdx.x;
    float val = (i < NE) ? arr[i] : 0.f;
    float s = blockReduceSum(val * val, red);
    if (threadIdx.x == 0) atomicAdd(&normAcc[slot], s);
}

// Exclusive prefix sum over NE=8192 ints, single block of 256 threads.
__global__ void k_scan(const int* __restrict__ cnt, int* ptr, int* cur) {
    __shared__ int sums[256];
    int tid = threadIdx.x;
    int base = tid * 32;
    int local[32];
    int s = 0;
    #pragma unroll
    for (int j = 0; j < 32; ++j) { local[j] = cnt[base + j]; s += local[j]; }
    sums[tid] = s;
    __syncthreads();
    for (int off = 1; off < 256; off <<= 1) {
        int t = (tid >= off) ? sums[tid - off] : 0;
        __syncthreads();
        sums[tid] += t;
        __syncthreads();
    }
    int run = (tid > 0) ? sums[tid - 1] : 0;
    #pragma unroll
    for (int j = 0; j < 32; ++j) { ptr[base + j] = run; cur[base + j] = run; run += local[j]; }
    if (tid == 255) ptr[NE] = run;
}

__global__ void k_sortpairs(const int* __restrict__ key, const int* __restrict__ other,
                            const float* __restrict__ v, int nnz,
                            int* cur, int2* pairs) {
    int idx = blockIdx.x * blockDim.x + threadIdx.x;
    int stride = gridDim.x * blockDim.x;
    for (int n = idx; n < nnz; n += stride) {
        int p = atomicAdd(&cur[key[n]], 1);
        pairs[p] = make_int2(other[n], __float_as_int(v[n]));
    }
}

// One block per row: build sparse row in LDS, 3-level db3 DWT in LDS,
// emit dirichlet weight w = clip(low)/(clip(low)+clip(high)).
__global__ __launch_bounds__(256) void k_rows(const int* __restrict__ ptr,
                                              const int2* __restrict__ pairs,
                                              const float* __restrict__ scaleArr,
                                              float* __restrict__ w_out) {
    __shared__ float bufA[NE];
    __shared__ float bufB[4104];
    __shared__ float red[4];
    int tid = threadIdx.x;
    int r = blockIdx.x;

    for (int j = tid; j < NE; j += 256) bufA[j] = 0.f;
    __syncthreads();
    int beg = ptr[r], end = ptr[r + 1];
    for (int n = beg + tid; n < end; n += 256) {
        int2 pr = pairs[n];
        atomicAdd(&bufA[pr.x], __int_as_float(pr.y));
    }
    __syncthreads();

    float high = 0.f;  // accumulated on thread 0 only

    // Level 1: bufA (N=8192) -> bufB (4098)
    float hsq = 0.f;
    for (int k = tid; k < 4098; k += 256) {
        float lo = 0.f, hi = 0.f;
        int base = 2 * k - 4;
        #pragma unroll
        for (int j = 0; j < 6; ++j) {
            int idx = base + j;
            float x = (idx >= 0 && idx < NE) ? bufA[idx] : 0.f;
            lo = fmaf(x, LO_R[j], lo);
            hi = fmaf(x, HI_R[j], hi);
        }
        bufB[k] = lo;
        hsq += hi * hi;
    }
    { float s = blockReduceSum(hsq, red); if (tid == 0) high += sqrtf(s); }
    __syncthreads();

    // Level 2: bufB (N=4098) -> bufA (2051)
    hsq = 0.f;
    for (int k = tid; k < 2051; k += 256) {
        float lo = 0.f, hi = 0.f;
        int base = 2 * k - 4;
        #pragma unroll
        for (int j = 0; j < 6; ++j) {
            int idx = base + j;
            float x = (idx >= 0 && idx < 4098) ? bufB[idx] : 0.f;
            lo = fmaf(x, LO_R[j], lo);
            hi = fmaf(x, HI_R[j], hi);
        }
        bufA[k] = lo;
        hsq += hi * hi;
    }
    { float s = blockReduceSum(hsq, red); if (tid == 0) high += sqrtf(s); }
    __syncthreads();

    // Level 3: bufA (N=2051) -> bufB (1028)
    hsq = 0.f;
    for (int k = tid; k < 1028; k += 256) {
        float lo = 0.f, hi = 0.f;
        int base = 2 * k - 4;
        #pragma unroll
        for (int j = 0; j < 6; ++j) {
            int idx = base + j;
            float x = (idx >= 0 && idx < 2051) ? bufA[idx] : 0.f;
            lo = fmaf(x, LO_R[j], lo);
            hi = fmaf(x, HI_R[j], hi);
        }
        bufB[k] = lo;
        hsq += hi * hi;
    }
    { float s = blockReduceSum(hsq, red); if (tid == 0) high += sqrtf(s); }
    __syncthreads();

    // mean of final low-pass (1028 elements)
    float ls = 0.f;
    for (int k = tid; k < 1028; k += 256) ls += bufB[k];
    float s = blockReduceSum(ls, red);
    if (tid == 0) {
        float sc = 1.f + scaleArr[r];
        float lowv = sc * (s / 1028.f);
        float highv = sc * high;
        float a1 = fmaxf(lowv, 1e-6f);
        float a2 = fmaxf(highv, 1e-6f);
        w_out[r] = a1 / (a1 + a2);
    }
}

__global__ void k_out(const int* __restrict__ ui, const int* __restrict__ ii,
                      const float* __restrict__ v, int nnz,
                      const float* __restrict__ u_w, const float* __restrict__ i_w,
                      float* __restrict__ out) {
    int idx = blockIdx.x * blockDim.x + threadIdx.x;
    int stride = gridDim.x * blockDim.x;
    for (int n = idx; n < nnz; n += stride) {
        float val = v[n];
        float wu = u_w[ui[n]], wi = i_w[ii[n]];
        float wun = 1.f - wu, win = 1.f - wi;
        out[n] = val * wu * wi;
        out[(size_t)nnz + n] = val * wun * win;
        out[2 * (size_t)nnz + n] = val * wu * win;
        out[3 * (size_t)nnz + n] = val * wun * wi;
    }
}

extern "C" void kernel_launch(void* const* d_in, const int* in_sizes, int n_in,
                              void* d_out, int out_size, void* d_ws, size_t ws_size,
                              hipStream_t stream) {
    const int* ui = (const int*)d_in[0];
    const int* ii = (const int*)d_in[1];
    const float* vals = (const float*)d_in[2];
    int nnz = in_sizes[0];
    float* out = (float*)d_out;

    char* ws = (char*)d_ws;
    size_t off = 0;
    auto take = [&](size_t bytes) -> char* {
        char* p = ws + off;
        off = (off + bytes + 255) & ~(size_t)255;
        return p;
    };

    int*   cntU    = (int*)take(NE * 4);
    int*   cntI    = (int*)take(NE * 4);
    float* sumvI   = (float*)take(NE * 4);
    float* actU    = (float*)take(NE * 4);
    float* normAcc = (float*)take(256);
    size_t zeroBytes = off;  // cntU..normAcc contiguous from ws start
    float* popI    = (float*)take(NE * 4);
    int*   ptrU    = (int*)take((NE + 1) * 4);
    int*   curU    = (int*)take(NE * 4);
    int*   ptrI    = (int*)take((NE + 1) * 4);
    int*   curI    = (int*)take(NE * 4);
    float* u_w     = (float*)take(NE * 4);
    float* i_w     = (float*)take(NE * 4);
    int2*  pairs   = (int2*)take((size_t)nnz * 8);

    hipMemsetAsync(ws, 0, zeroBytes, stream);

    int nb = (nnz + 255) / 256;
    if (nb > 8192) nb = 8192;
    const int ne_blocks = NE / 256;

    k_count<<<nb, 256, 0, stream>>>(ui, ii, vals, nnz, cntU, cntI, sumvI);
    k_pop_raw<<<ne_blocks, 256, 0, stream>>>(cntI, sumvI, popI, normAcc);
    k_scale<<<ne_blocks, 256, 0, stream>>>(popI, normAcc, 0);
    k_act<<<nb, 256, 0, stream>>>(ui, ii, vals, nnz, popI, actU);
    k_sumsq<<<ne_blocks, 256, 0, stream>>>(actU, normAcc, 1);
    k_scale<<<ne_blocks, 256, 0, stream>>>(actU, normAcc, 1);

    // users: sort by user, per-row DWT -> u_w
    k_scan<<<1, 256, 0, stream>>>(cntU, ptrU, curU);
    k_sortpairs<<<nb, 256, 0, stream>>>(ui, ii, vals, nnz, curU, pairs);
    k_rows<<<NE, 256, 0, stream>>>(ptrU, pairs, actU, u_w);

    // items: sort by item (reuse pairs buffer), per-row DWT -> i_w
    k_scan<<<1, 256, 0, stream>>>(cntI, ptrI, curI);
    k_sortpairs<<<nb, 256, 0, stream>>>(ii, ui, vals, nnz, curI, pairs);
    k_rows<<<NE, 256, 0, stream>>>(ptrI, pairs, popI, i_w);

    k_out<<<nb, 256, 0, stream>>>(ui, ii, vals, nnz, u_w, i_w, out);
}

// Round 2
// 454.071 us; speedup vs baseline: 1.8547x; 1.8547x over previous
//
#include <hip/hip_runtime.h>
#include <math.h>

#define NE 8192  // num_users == num_items (fixed by reference setup_inputs)
#define HT 512   // histogram/scatter block threads

// db3 analysis filters, reversed (cross-correlation of reversed filter == convolution)
__device__ __constant__ float LO_R[6] = {
    0.3326705529509569f, 0.8068915093133388f, 0.4598775021193313f,
    -0.13501102001039084f, -0.08544127388224149f, 0.035226291882100656f};
__device__ __constant__ float HI_R[6] = {
    0.035226291882100656f, 0.08544127388224149f, -0.13501102001039084f,
    -0.4598775021193313f, 0.8068915093133388f, -0.3326705529509569f};

// Block reduce: result valid on thread 0 only. Caller must __syncthreads()
// after consuming the result before red[] is reused.
__device__ __forceinline__ float blockReduceSum(float v, float* red) {
    #pragma unroll
    for (int off = 32; off > 0; off >>= 1) v += __shfl_down(v, off);
    int lane = threadIdx.x & 63, wid = threadIdx.x >> 6;
    if (lane == 0) red[wid] = v;
    __syncthreads();
    float r = 0.f;
    if (threadIdx.x == 0) {
        int nw = blockDim.x >> 6;
        for (int i = 0; i < nw; ++i) r += red[i];
    }
    return r;
}

// LDS-privatized 3-table histogram; writes per-block slices (no global atomics).
__global__ __launch_bounds__(HT) void k_hist3(const int* __restrict__ ui,
                                              const int* __restrict__ ii,
                                              const float* __restrict__ v, int nnz,
                                              int* __restrict__ sliceU,
                                              int* __restrict__ sliceI,
                                              float* __restrict__ sliceS) {
    __shared__ int hU[NE];
    __shared__ int hI[NE];
    __shared__ float hS[NE];
    int b = blockIdx.x, tid = threadIdx.x, hb = gridDim.x;
    for (int j = tid; j < NE; j += HT) { hU[j] = 0; hI[j] = 0; hS[j] = 0.f; }
    __syncthreads();
    int C = (nnz + hb - 1) / hb;
    int beg = b * C, end = min(nnz, beg + C);
    for (int n = beg + tid; n < end; n += HT) {
        int u = ui[n], it = ii[n];
        float val = v[n];
        atomicAdd(&hU[u], 1);
        atomicAdd(&hI[it], 1);
        atomicAdd(&hS[it], val);
    }
    __syncthreads();
    size_t base = (size_t)b * NE;
    for (int j = tid; j < NE; j += HT) {
        sliceU[base + j] = hU[j];
        sliceI[base + j] = hI[j];
        sliceS[base + j] = hS[j];
    }
}

// Column-sum slices -> final tables + pop_raw + ||pop_raw||^2
__global__ void k_reduce3(const int* __restrict__ sliceU, const int* __restrict__ sliceI,
                          const float* __restrict__ sliceS, int hb,
                          int* cntU, int* cntI, float* popraw, float* normAcc) {
    __shared__ float red[4];
    int i = blockIdx.x * blockDim.x + threadIdx.x;
    int cu = 0, ci = 0; float sv = 0.f;
    for (int b = 0; b < hb; ++b) {
        size_t o = (size_t)b * NE + i;
        cu += sliceU[o];
        ci += sliceI[o];
        sv += sliceS[o];
    }
    cntU[i] = cu; cntI[i] = ci;
    float p = log1pf((float)ci) * sv;
    popraw[i] = p;
    float s = blockReduceSum(p * p, red);
    if (threadIdx.x == 0) atomicAdd(&normAcc[0], s);
}

__global__ void k_scale(float* arr, const float* __restrict__ normAcc, int slot) {
    int i = blockIdx.x * blockDim.x + threadIdx.x;
    float sc = 1.f / (sqrtf(normAcc[slot]) + 1e-8f);
    if (i < NE) arr[i] *= sc;
}

// LDS-privatized activity histogram
__global__ __launch_bounds__(HT) void k_acthist(const int* __restrict__ ui,
                                                const int* __restrict__ ii,
                                                const float* __restrict__ v, int nnz,
                                                const float* __restrict__ pop,
                                                float* __restrict__ sliceA) {
    __shared__ float hA[NE];
    int b = blockIdx.x, tid = threadIdx.x, hb = gridDim.x;
    for (int j = tid; j < NE; j += HT) hA[j] = 0.f;
    __syncthreads();
    int C = (nnz + hb - 1) / hb;
    int beg = b * C, end = min(nnz, beg + C);
    for (int n = beg + tid; n < end; n += HT) {
        atomicAdd(&hA[ui[n]], v[n] / log1pf(pop[ii[n]] + 1e-8f));
    }
    __syncthreads();
    size_t base = (size_t)b * NE;
    for (int j = tid; j < NE; j += HT) sliceA[base + j] = hA[j];
}

__global__ void k_actreduce(const float* __restrict__ sliceA, int hb,
                            float* act, float* normAcc) {
    __shared__ float red[4];
    int i = blockIdx.x * blockDim.x + threadIdx.x;
    float a = 0.f;
    for (int b = 0; b < hb; ++b) a += sliceA[(size_t)b * NE + i];
    act[i] = a;
    float s = blockReduceSum(a * a, red);
    if (threadIdx.x == 0) atomicAdd(&normAcc[1], s);
}

// Exclusive prefix sum over NE=8192 ints, single block of 256 threads.
__global__ void k_scan(const int* __restrict__ cnt, int* ptr) {
    __shared__ int sums[256];
    int tid = threadIdx.x;
    int base = tid * 32;
    int local[32];
    int s = 0;
    #pragma unroll
    for (int j = 0; j < 32; ++j) { local[j] = cnt[base + j]; s += local[j]; }
    sums[tid] = s;
    __syncthreads();
    for (int off = 1; off < 256; off <<= 1) {
        int t = (tid >= off) ? sums[tid - off] : 0;
        __syncthreads();
        sums[tid] += t;
        __syncthreads();
    }
    int run = (tid > 0) ? sums[tid - 1] : 0;
    #pragma unroll
    for (int j = 0; j < 32; ++j) { ptr[base + j] = run; run += local[j]; }
    if (tid == 255) ptr[NE] = run;
}

// Column-wise exclusive scan of slice matrix seeded with ptr -> per-block offsets (in place)
__global__ void k_colscan(int* slice, const int* __restrict__ ptr, int hb) {
    int i = blockIdx.x * blockDim.x + threadIdx.x;
    int run = ptr[i];
    for (int b = 0; b < hb; ++b) {
        size_t o = (size_t)b * NE + i;
        int t = slice[o];
        slice[o] = run;
        run += t;
    }
}

// Deterministic scatter using per-block LDS cursors (no global atomics)
__global__ __launch_bounds__(HT) void k_scatter(const int* __restrict__ key,
                                                const int* __restrict__ other,
                                                const float* __restrict__ v, int nnz,
                                                const int* __restrict__ sliceOff,
                                                int2* __restrict__ pairs) {
    __shared__ int cur[NE];
    int b = blockIdx.x, tid = threadIdx.x, hb = gridDim.x;
    size_t base = (size_t)b * NE;
    for (int j = tid; j < NE; j += HT) cur[j] = sliceOff[base + j];
    __syncthreads();
    int C = (nnz + hb - 1) / hb;
    int beg = b * C, end = min(nnz, beg + C);
    for (int n = beg + tid; n < end; n += HT) {
        int k = key[n];
        int p = atomicAdd(&cur[k], 1);
        pairs[p] = make_int2(other[n], __float_as_int(v[n]));
    }
}

// One DWT analysis level from padded LDS buffer X (X[i] = x[i-4], zeros outside)
// to padded Y (writes Y[4+k]). Each thread computes an output pair from two
// float4 LDS loads (conflict-free stride-16B ds_read_b128).
__device__ __forceinline__ float dwt_level(const float* __restrict__ X,
                                           float* __restrict__ Y,
                                           int outsize, int tid) {
    const float4* X4 = (const float4*)X;
    float hsq = 0.f;
    int ngroups = (outsize + 1) >> 1;
    for (int g = tid; g < ngroups; g += 256) {
        float4 a = X4[g];      // x[4g-4 .. 4g-1]
        float4 b = X4[g + 1];  // x[4g   .. 4g+3]
        float lo0 = a.x * LO_R[0], hi0 = a.x * HI_R[0];
        lo0 = fmaf(a.y, LO_R[1], lo0); hi0 = fmaf(a.y, HI_R[1], hi0);
        lo0 = fmaf(a.z, LO_R[2], lo0); hi0 = fmaf(a.z, HI_R[2], hi0);
        lo0 = fmaf(a.w, LO_R[3], lo0); hi0 = fmaf(a.w, HI_R[3], hi0);
        lo0 = fmaf(b.x, LO_R[4], lo0); hi0 = fmaf(b.x, HI_R[4], hi0);
        lo0 = fmaf(b.y, LO_R[5], lo0); hi0 = fmaf(b.y, HI_R[5], hi0);
        float lo1 = a.z * LO_R[0], hi1 = a.z * HI_R[0];
        lo1 = fmaf(a.w, LO_R[1], lo1); hi1 = fmaf(a.w, HI_R[1], hi1);
        lo1 = fmaf(b.x, LO_R[2], lo1); hi1 = fmaf(b.x, HI_R[2], hi1);
        lo1 = fmaf(b.y, LO_R[3], lo1); hi1 = fmaf(b.y, HI_R[3], hi1);
        lo1 = fmaf(b.z, LO_R[4], lo1); hi1 = fmaf(b.z, HI_R[4], hi1);
        lo1 = fmaf(b.w, LO_R[5], lo1); hi1 = fmaf(b.w, HI_R[5], hi1);
        int k = 2 * g;
        Y[4 + k] = lo0;
        hsq += hi0 * hi0;
        if (k + 1 < outsize) { Y[4 + k + 1] = lo1; hsq += hi1 * hi1; }
    }
    return hsq;
}

// One block per row: build sparse row in LDS, 3-level db3 DWT in LDS,
// emit dirichlet weight w = clip(low)/(clip(low)+clip(high)).
__global__ __launch_bounds__(256) void k_rows(const int* __restrict__ ptr,
                                              const int2* __restrict__ pairs,
                                              const float* __restrict__ scaleArr,
                                              float* __restrict__ w_out) {
    __shared__ __align__(16) float bufA[8208];  // 4 front pad + 8192 + tail pad
    __shared__ __align__(16) float bufB[4112];  // 4 front pad + 4098 + tail pad
    __shared__ float red[4];
    int tid = threadIdx.x, r = blockIdx.x;
    float4* A4 = (float4*)bufA;
    float4* B4 = (float4*)bufB;
    for (int j = tid; j < 2052; j += 256) A4[j] = make_float4(0.f, 0.f, 0.f, 0.f);
    for (int j = tid; j < 1028; j += 256) B4[j] = make_float4(0.f, 0.f, 0.f, 0.f);
    __syncthreads();
    int beg = ptr[r], end = ptr[r + 1];
    for (int n = beg + tid; n < end; n += 256) {
        int2 pr = pairs[n];
        atomicAdd(&bufA[4 + pr.x], __int_as_float(pr.y));
    }
    __syncthreads();

    float high = 0.f;  // thread 0 only

    float hsq = dwt_level(bufA, bufB, 4098, tid);
    { float s = blockReduceSum(hsq, red); if (tid == 0) high += sqrtf(s); }
    __syncthreads();

    hsq = dwt_level(bufB, bufA, 2051, tid);
    { float s = blockReduceSum(hsq, red); if (tid == 0) high += sqrtf(s); }
    // zero stale tail of bufA (level-2 payload ends at idx 2054; level 3 reads to 2059)
    if (tid < 16) bufA[2055 + tid] = 0.f;
    __syncthreads();

    hsq = dwt_level(bufA, bufB, 1028, tid);
    { float s = blockReduceSum(hsq, red); if (tid == 0) high += sqrtf(s); }
    __syncthreads();

    float ls = 0.f;
    for (int k = tid; k < 1028; k += 256) ls += bufB[4 + k];
    float s = blockReduceSum(ls, red);
    if (tid == 0) {
        float sc = 1.f + scaleArr[r];
        float lowv = sc * (s / 1028.f);
        float highv = sc * high;
        float a1 = fmaxf(lowv, 1e-6f);
        float a2 = fmaxf(highv, 1e-6f);
        w_out[r] = a1 / (a1 + a2);
    }
}

__global__ void k_out(const int* __restrict__ ui, const int* __restrict__ ii,
                      const float* __restrict__ v, int nnz,
                      const float* __restrict__ u_w, const float* __restrict__ i_w,
                      float* __restrict__ out) {
    int idx = blockIdx.x * blockDim.x + threadIdx.x;
    int stride = gridDim.x * blockDim.x;
    for (int n = idx; n < nnz; n += stride) {
        float val = v[n];
        float wu = u_w[ui[n]], wi = i_w[ii[n]];
        float wun = 1.f - wu, win = 1.f - wi;
        out[n] = val * wu * wi;
        out[(size_t)nnz + n] = val * wun * win;
        out[2 * (size_t)nnz + n] = val * wu * win;
        out[3 * (size_t)nnz + n] = val * wun * wi;
    }
}

extern "C" void kernel_launch(void* const* d_in, const int* in_sizes, int n_in,
                              void* d_out, int out_size, void* d_ws, size_t ws_size,
                              hipStream_t stream) {
    const int* ui = (const int*)d_in[0];
    const int* ii = (const int*)d_in[1];
    const float* vals = (const float*)d_in[2];
    int nnz = in_sizes[0];
    float* out = (float*)d_out;

    char* ws = (char*)d_ws;
    size_t off = 0;
    auto take = [&](size_t bytes) -> char* {
        char* p = ws + off;
        off = (off + bytes + 255) & ~(size_t)255;
        return p;
    };

    int*   cntU    = (int*)take(NE * 4);
    int*   cntI    = (int*)take(NE * 4);
    float* popI    = (float*)take(NE * 4);
    float* actU    = (float*)take(NE * 4);
    int*   ptrU    = (int*)take((NE + 1) * 4);
    int*   ptrI    = (int*)take((NE + 1) * 4);
    float* u_w     = (float*)take(NE * 4);
    float* i_w     = (float*)take(NE * 4);
    float* normAcc = (float*)take(256);
    int2*  pairs   = (int2*)take((size_t)nnz * 8);
    size_t fixedEnd = off;

    // adaptive histogram-block count so slices fit in ws
    int hb = 128;
    while (hb > 8 && fixedEnd + 3 * (size_t)hb * NE * 4 + 1024 > ws_size) hb >>= 1;
    int*   sliceU = (int*)take((size_t)hb * NE * 4);
    int*   sliceI = (int*)take((size_t)hb * NE * 4);
    float* sliceS = (float*)take((size_t)hb * NE * 4);  // reused as sliceAct

    hipMemsetAsync(normAcc, 0, 256, stream);

    int nb = (nnz + 255) / 256;
    if (nb > 8192) nb = 8192;
    const int ne_blocks = NE / 256;  // 32

    // popularity + counts (no global atomics)
    k_hist3<<<hb, HT, 0, stream>>>(ui, ii, vals, nnz, sliceU, sliceI, sliceS);
    k_reduce3<<<ne_blocks, 256, 0, stream>>>(sliceU, sliceI, sliceS, hb,
                                             cntU, cntI, popI, normAcc);
    k_scale<<<ne_blocks, 256, 0, stream>>>(popI, normAcc, 0);

    // user activity
    k_acthist<<<hb, HT, 0, stream>>>(ui, ii, vals, nnz, popI, (float*)sliceS);
    k_actreduce<<<ne_blocks, 256, 0, stream>>>((float*)sliceS, hb, actU, normAcc);
    k_scale<<<ne_blocks, 256, 0, stream>>>(actU, normAcc, 1);

    // users: deterministic counting sort by user, per-row DWT -> u_w
    k_scan<<<1, 256, 0, stream>>>(cntU, ptrU);
    k_colscan<<<ne_blocks, 256, 0, stream>>>(sliceU, ptrU, hb);
    k_scatter<<<hb, HT, 0, stream>>>(ui, ii, vals, nnz, sliceU, pairs);
    k_rows<<<NE, 256, 0, stream>>>(ptrU, pairs, actU, u_w);

    // items: counting sort by item (reuse pairs), per-row DWT -> i_w
    k_scan<<<1, 256, 0, stream>>>(cntI, ptrI);
    k_colscan<<<ne_blocks, 256, 0, stream>>>(sliceI, ptrI, hb);
    k_scatter<<<hb, HT, 0, stream>>>(ii, ui, vals, nnz, sliceI, pairs);
    k_rows<<<NE, 256, 0, stream>>>(ptrI, pairs, popI, i_w);

    k_out<<<nb, 256, 0, stream>>>(ui, ii, vals, nnz, u_w, i_w, out);
}

// Round 3
// 361.497 us; speedup vs baseline: 2.3296x; 1.2561x over previous
//
#include <hip/hip_runtime.h>
#include <math.h>

#define NE 8192   // num_users == num_items
#define HT 1024   // histogram/scatter block threads
#define RT 512    // k_rows block threads
#define NCH 8     // slice chunks for two-level colscan/reduce

// db3 analysis filters, reversed (cross-correlation of reversed filter == convolution)
__device__ __constant__ float LO_R[6] = {
    0.3326705529509569f, 0.8068915093133388f, 0.4598775021193313f,
    -0.13501102001039084f, -0.08544127388224149f, 0.035226291882100656f};
__device__ __constant__ float HI_R[6] = {
    0.035226291882100656f, 0.08544127388224149f, -0.13501102001039084f,
    -0.4598775021193313f, 0.8068915093133388f, -0.3326705529509569f};

// 256-thread block reduce; valid on thread 0.
__device__ __forceinline__ float blockReduceSum(float v, float* red) {
    #pragma unroll
    for (int off = 32; off > 0; off >>= 1) v += __shfl_down(v, off);
    int lane = threadIdx.x & 63, wid = threadIdx.x >> 6;
    if (lane == 0) red[wid] = v;
    __syncthreads();
    float r = 0.f;
    if (threadIdx.x == 0) {
        int nw = blockDim.x >> 6;
        for (int i = 0; i < nw; ++i) r += red[i];
    }
    return r;
}

// 4-value fused block reduce for RT-thread blocks; valid on thread 0.
__device__ __forceinline__ float4 blockReduce4(float a, float b, float c, float d,
                                               float (*red)[4]) {
    #pragma unroll
    for (int off = 32; off > 0; off >>= 1) {
        a += __shfl_down(a, off); b += __shfl_down(b, off);
        c += __shfl_down(c, off); d += __shfl_down(d, off);
    }
    int lane = threadIdx.x & 63, wid = threadIdx.x >> 6;
    if (lane == 0) { red[wid][0] = a; red[wid][1] = b; red[wid][2] = c; red[wid][3] = d; }
    __syncthreads();
    float4 r = make_float4(0.f, 0.f, 0.f, 0.f);
    if (threadIdx.x == 0) {
        int nw = blockDim.x >> 6;
        for (int w = 0; w < nw; ++w) {
            r.x += red[w][0]; r.y += red[w][1]; r.z += red[w][2]; r.w += red[w][3];
        }
    }
    return r;
}

__global__ __launch_bounds__(HT) void k_hist3(const int* __restrict__ ui,
                                              const int* __restrict__ ii,
                                              const float* __restrict__ v, int nnz,
                                              int* __restrict__ sliceU,
                                              int* __restrict__ sliceI,
                                              float* __restrict__ sliceS) {
    __shared__ int hU[NE];
    __shared__ int hI[NE];
    __shared__ float hS[NE];
    int b = blockIdx.x, tid = threadIdx.x, hb = gridDim.x;
    int4* hU4 = (int4*)hU; int4* hI4 = (int4*)hI; int4* hS4 = (int4*)hS;
    int4 z4 = make_int4(0, 0, 0, 0);
    for (int j = tid; j < NE / 4; j += HT) { hU4[j] = z4; hI4[j] = z4; hS4[j] = z4; }
    __syncthreads();
    int C = (nnz + hb - 1) / hb;
    int beg = b * C, end = min(nnz, beg + C);
    for (int n = beg + tid; n < end; n += HT) {
        atomicAdd(&hU[ui[n]], 1);
        int it = ii[n];
        atomicAdd(&hI[it], 1);
        atomicAdd(&hS[it], v[n]);
    }
    __syncthreads();
    size_t base = (size_t)b * NE;
    int4* sU = (int4*)(sliceU + base); int4* sI = (int4*)(sliceI + base);
    int4* sS = (int4*)(sliceS + base);
    for (int j = tid; j < NE / 4; j += HT) { sU[j] = hU4[j]; sI[j] = hI4[j]; sS[j] = hS4[j]; }
}

// grid (32, NCH): per-chunk column sums of the three slice matrices
__global__ void k_chunksum3(const int* __restrict__ sliceU, const int* __restrict__ sliceI,
                            const float* __restrict__ sliceS, int spc,
                            int* __restrict__ csU, int* __restrict__ csI,
                            float* __restrict__ csS) {
    int i = blockIdx.x * 256 + threadIdx.x;
    int c = blockIdx.y;
    int b0 = c * spc;
    int cu = 0, ci = 0; float sv = 0.f;
    for (int b = b0; b < b0 + spc; ++b) {
        size_t o = (size_t)b * NE + i;
        cu += sliceU[o]; ci += sliceI[o]; sv += sliceS[o];
    }
    size_t oc = (size_t)c * NE + i;
    csU[oc] = cu; csI[oc] = ci; csS[oc] = sv;
}

__global__ void k_final3(const int* __restrict__ csU, const int* __restrict__ csI,
                         const float* __restrict__ csS,
                         int* cntU, int* cntI, float* popraw, float* normAcc) {
    __shared__ float red[4];
    int i = blockIdx.x * 256 + threadIdx.x;
    int cu = 0, ci = 0; float sv = 0.f;
    #pragma unroll
    for (int c = 0; c < NCH; ++c) {
        size_t o = (size_t)c * NE + i;
        cu += csU[o]; ci += csI[o]; sv += csS[o];
    }
    cntU[i] = cu; cntI[i] = ci;
    float p = log1pf((float)ci) * sv;
    popraw[i] = p;
    float s = blockReduceSum(p * p, red);
    if (threadIdx.x == 0) atomicAdd(&normAcc[0], s);
}

__global__ void k_scale(float* arr, const float* __restrict__ normAcc, int slot) {
    int i = blockIdx.x * 256 + threadIdx.x;
    float sc = 1.f / (sqrtf(normAcc[slot]) + 1e-8f);
    if (i < NE) arr[i] *= sc;
}

__global__ __launch_bounds__(HT) void k_acthist(const int* __restrict__ ui,
                                                const int* __restrict__ ii,
                                                const float* __restrict__ v, int nnz,
                                                const float* __restrict__ pop,
                                                float* __restrict__ sliceA) {
    __shared__ float hA[NE];
    int b = blockIdx.x, tid = threadIdx.x, hb = gridDim.x;
    float4* hA4 = (float4*)hA;
    float4 z4 = make_float4(0.f, 0.f, 0.f, 0.f);
    for (int j = tid; j < NE / 4; j += HT) hA4[j] = z4;
    __syncthreads();
    int C = (nnz + hb - 1) / hb;
    int beg = b * C, end = min(nnz, beg + C);
    for (int n = beg + tid; n < end; n += HT) {
        atomicAdd(&hA[ui[n]], v[n] / log1pf(pop[ii[n]] + 1e-8f));
    }
    __syncthreads();
    float4* sA = (float4*)(sliceA + (size_t)b * NE);
    for (int j = tid; j < NE / 4; j += HT) sA[j] = hA4[j];
}

__global__ void k_actchunk(const float* __restrict__ sliceA, int spc, float* __restrict__ csA) {
    int i = blockIdx.x * 256 + threadIdx.x;
    int c = blockIdx.y;
    int b0 = c * spc;
    float a = 0.f;
    for (int b = b0; b < b0 + spc; ++b) a += sliceA[(size_t)b * NE + i];
    csA[(size_t)c * NE + i] = a;
}

__global__ void k_actfinal(const float* __restrict__ csA, float* act, float* normAcc) {
    __shared__ float red[4];
    int i = blockIdx.x * 256 + threadIdx.x;
    float a = 0.f;
    #pragma unroll
    for (int c = 0; c < NCH; ++c) a += csA[(size_t)c * NE + i];
    act[i] = a;
    float s = blockReduceSum(a * a, red);
    if (threadIdx.x == 0) atomicAdd(&normAcc[1], s);
}

// grid 2: exclusive prefix sums for both tables
__global__ void k_scan2(const int* __restrict__ cntU, const int* __restrict__ cntI,
                        int* ptrU, int* ptrI) {
    __shared__ int sums[256];
    const int* cnt = blockIdx.x ? cntI : cntU;
    int* ptr = blockIdx.x ? ptrI : ptrU;
    int tid = threadIdx.x;
    int base = tid * 32;
    int local[32];
    int s = 0;
    #pragma unroll
    for (int j = 0; j < 32; ++j) { local[j] = cnt[base + j]; s += local[j]; }
    sums[tid] = s;
    __syncthreads();
    for (int off = 1; off < 256; off <<= 1) {
        int t = (tid >= off) ? sums[tid - off] : 0;
        __syncthreads();
        sums[tid] += t;
        __syncthreads();
    }
    int run = (tid > 0) ? sums[tid - 1] : 0;
    #pragma unroll
    for (int j = 0; j < 32; ++j) { ptr[base + j] = run; run += local[j]; }
    if (tid == 255) ptr[NE] = run;
}

// grid (32, 2): scan chunk sums (in place) seeded with ptr
__global__ void k_colscanB(int* csU, int* csI,
                           const int* __restrict__ ptrU, const int* __restrict__ ptrI) {
    int i = blockIdx.x * 256 + threadIdx.x;
    int* cs = blockIdx.y ? csI : csU;
    const int* ptr = blockIdx.y ? ptrI : ptrU;
    int run = ptr[i];
    #pragma unroll
    for (int c = 0; c < NCH; ++c) {
        size_t o = (size_t)c * NE + i;
        int t = cs[o]; cs[o] = run; run += t;
    }
}

// grid (32, NCH, 2): within-chunk scan of slices (in place) seeded with chunk offsets
__global__ void k_colscanC(int* sliceU, int* sliceI,
                           const int* __restrict__ csU, const int* __restrict__ csI, int spc) {
    int i = blockIdx.x * 256 + threadIdx.x;
    int c = blockIdx.y;
    int* slice = blockIdx.z ? sliceI : sliceU;
    const int* cs = blockIdx.z ? csI : csU;
    int run = cs[(size_t)c * NE + i];
    int b0 = c * spc;
    for (int b = b0; b < b0 + spc; ++b) {
        size_t o = (size_t)b * NE + i;
        int t = slice[o]; slice[o] = run; run += t;
    }
}

__global__ __launch_bounds__(HT) void k_scatter(const int* __restrict__ key,
                                                const int* __restrict__ other,
                                                const float* __restrict__ v, int nnz,
                                                const int* __restrict__ sliceOff,
                                                int2* __restrict__ pairs) {
    __shared__ int cur[NE];
    int b = blockIdx.x, tid = threadIdx.x, hb = gridDim.x;
    const int4* src = (const int4*)(sliceOff + (size_t)b * NE);
    int4* c4 = (int4*)cur;
    for (int j = tid; j < NE / 4; j += HT) c4[j] = src[j];
    __syncthreads();
    int C = (nnz + hb - 1) / hb;
    int beg = b * C, end = min(nnz, beg + C);
    for (int n = beg + tid; n < end; n += HT) {
        int k = key[n];
        int p = atomicAdd(&cur[k], 1);
        pairs[p] = make_int2(other[n], __float_as_int(v[n]));
    }
}

// One block per row. Level 1 via sparse scatter (6 LDS-atomic FMAs per nnz)
// into lo1 (A) / hi1 (B); levels 2-3 dense from LDS; lo3 only summed.
__global__ __launch_bounds__(RT) void k_rows(const int* __restrict__ ptr,
                                             const int2* __restrict__ pairs,
                                             const float* __restrict__ scaleArr,
                                             float* __restrict__ w_out) {
    __shared__ __align__(16) float A[4112];  // lo1: A[4+k], k<4098; zero pad elsewhere
    __shared__ __align__(16) float B[4112];  // hi1 then lo2
    __shared__ float red[RT / 64][4];
    int tid = threadIdx.x, r = blockIdx.x;
    float4* A4 = (float4*)A; float4* B4 = (float4*)B;
    float4 z4 = make_float4(0.f, 0.f, 0.f, 0.f);
    for (int j = tid; j < 1028; j += RT) { A4[j] = z4; B4[j] = z4; }
    __syncthreads();

    int beg = ptr[r], end = ptr[r + 1];
    for (int n = beg + tid; n < end; n += RT) {
        int2 pr = pairs[n];
        float v = __int_as_float(pr.y);
        int p = pr.x;
        int par = p & 1;
        int kb = (p >> 1) + 4;
        // x[p] -> lo1[k], hi1[k] for k = p>>1 + {0,1,2}, tap j = {4,2,0} + par
        float l0 = par ? LO_R[5] : LO_R[4], l1 = par ? LO_R[3] : LO_R[2], l2 = par ? LO_R[1] : LO_R[0];
        float h0 = par ? HI_R[5] : HI_R[4], h1 = par ? HI_R[3] : HI_R[2], h2 = par ? HI_R[1] : HI_R[0];
        atomicAdd(&A[kb],     v * l0);
        atomicAdd(&A[kb + 1], v * l1);
        atomicAdd(&A[kb + 2], v * l2);
        atomicAdd(&B[kb],     v * h0);
        atomicAdd(&B[kb + 1], v * h1);
        atomicAdd(&B[kb + 2], v * h2);
    }
    __syncthreads();

    // ||hi1||^2 over B[4..4101] (B[4102..4103] are zero) via groups B4[1..1025]
    float s1 = 0.f;
    for (int g = tid; g < 1025; g += RT) {
        float4 h = B4[1 + g];
        s1 += h.x * h.x + h.y * h.y + h.z * h.z + h.w * h.w;
    }
    __syncthreads();  // all hi1 reads done before lo2 overwrites B

    // Level 2: A (lo1, N=4098) -> B (lo2, 2051); hi2 in registers
    float s2 = 0.f, s3 = 0.f, ls = 0.f;
    for (int g = tid; g < 1026; g += RT) {
        float4 a = A4[g], b = A4[g + 1];
        float lo0 = a.x * LO_R[0], hi0 = a.x * HI_R[0];
        lo0 = fmaf(a.y, LO_R[1], lo0); hi0 = fmaf(a.y, HI_R[1], hi0);
        lo0 = fmaf(a.z, LO_R[2], lo0); hi0 = fmaf(a.z, HI_R[2], hi0);
        lo0 = fmaf(a.w, LO_R[3], lo0); hi0 = fmaf(a.w, HI_R[3], hi0);
        lo0 = fmaf(b.x, LO_R[4], lo0); hi0 = fmaf(b.x, HI_R[4], hi0);
        lo0 = fmaf(b.y, LO_R[5], lo0); hi0 = fmaf(b.y, HI_R[5], hi0);
        float lo1 = a.z * LO_R[0], hi1 = a.z * HI_R[0];
        lo1 = fmaf(a.w, LO_R[1], lo1); hi1 = fmaf(a.w, HI_R[1], hi1);
        lo1 = fmaf(b.x, LO_R[2], lo1); hi1 = fmaf(b.x, HI_R[2], hi1);
        lo1 = fmaf(b.y, LO_R[3], lo1); hi1 = fmaf(b.y, HI_R[3], hi1);
        lo1 = fmaf(b.z, LO_R[4], lo1); hi1 = fmaf(b.z, HI_R[4], hi1);
        lo1 = fmaf(b.w, LO_R[5], lo1); hi1 = fmaf(b.w, HI_R[5], hi1);
        int k = 2 * g;
        B[4 + k] = lo0;
        s2 += hi0 * hi0;
        if (k < 2050) { B[5 + k] = lo1; s2 += hi1 * hi1; }
    }
    if (tid < 16) B[2055 + tid] = 0.f;  // zero stale hi1 tail past lo2 payload
    __syncthreads();

    // Level 3: B (lo2, N=2051) -> registers only (1028 outputs, 514 full pairs)
    for (int g = tid; g < 514; g += RT) {
        float4 a = B4[g], b = B4[g + 1];
        float lo0 = a.x * LO_R[0], hi0 = a.x * HI_R[0];
        lo0 = fmaf(a.y, LO_R[1], lo0); hi0 = fmaf(a.y, HI_R[1], hi0);
        lo0 = fmaf(a.z, LO_R[2], lo0); hi0 = fmaf(a.z, HI_R[2], hi0);
        lo0 = fmaf(a.w, LO_R[3], lo0); hi0 = fmaf(a.w, HI_R[3], hi0);
        lo0 = fmaf(b.x, LO_R[4], lo0); hi0 = fmaf(b.x, HI_R[4], hi0);
        lo0 = fmaf(b.y, LO_R[5], lo0); hi0 = fmaf(b.y, HI_R[5], hi0);
        float lo1 = a.z * LO_R[0], hi1 = a.z * HI_R[0];
        lo1 = fmaf(a.w, LO_R[1], lo1); hi1 = fmaf(a.w, HI_R[1], hi1);
        lo1 = fmaf(b.x, LO_R[2], lo1); hi1 = fmaf(b.x, HI_R[2], hi1);
        lo1 = fmaf(b.y, LO_R[3], lo1); hi1 = fmaf(b.y, HI_R[3], hi1);
        lo1 = fmaf(b.z, LO_R[4], lo1); hi1 = fmaf(b.z, HI_R[4], hi1);
        lo1 = fmaf(b.w, LO_R[5], lo1); hi1 = fmaf(b.w, HI_R[5], hi1);
        ls += lo0 + lo1;
        s3 += hi0 * hi0 + hi1 * hi1;
    }

    float4 t = blockReduce4(s1, s2, s3, ls, red);
    if (tid == 0) {
        float high = sqrtf(t.x) + sqrtf(t.y) + sqrtf(t.z);
        float low = t.w * (1.f / 1028.f);
        float sc = 1.f + scaleArr[r];
        low *= sc; high *= sc;
        float a1 = fmaxf(low, 1e-6f);
        float a2 = fmaxf(high, 1e-6f);
        w_out[r] = a1 / (a1 + a2);
    }
}

__global__ void k_out(const int* __restrict__ ui, const int* __restrict__ ii,
                      const float* __restrict__ v, int nnz,
                      const float* __restrict__ u_w, const float* __restrict__ i_w,
                      float* __restrict__ out) {
    int idx = blockIdx.x * blockDim.x + threadIdx.x;
    int stride = gridDim.x * blockDim.x;
    for (int n = idx; n < nnz; n += stride) {
        float val = v[n];
        float wu = u_w[ui[n]], wi = i_w[ii[n]];
        float wun = 1.f - wu, win = 1.f - wi;
        out[n] = val * wu * wi;
        out[(size_t)nnz + n] = val * wun * win;
        out[2 * (size_t)nnz + n] = val * wu * win;
        out[3 * (size_t)nnz + n] = val * wun * wi;
    }
}

extern "C" void kernel_launch(void* const* d_in, const int* in_sizes, int n_in,
                              void* d_out, int out_size, void* d_ws, size_t ws_size,
                              hipStream_t stream) {
    const int* ui = (const int*)d_in[0];
    const int* ii = (const int*)d_in[1];
    const float* vals = (const float*)d_in[2];
    int nnz = in_sizes[0];
    float* out = (float*)d_out;

    char* ws = (char*)d_ws;
    size_t off = 0;
    auto take = [&](size_t bytes) -> char* {
        char* p = ws + off;
        off = (off + bytes + 255) & ~(size_t)255;
        return p;
    };

    int*   cntU    = (int*)take(NE * 4);
    int*   cntI    = (int*)take(NE * 4);
    float* popI    = (float*)take(NE * 4);
    float* actU    = (float*)take(NE * 4);
    int*   ptrU    = (int*)take((NE + 1) * 4);
    int*   ptrI    = (int*)take((NE + 1) * 4);
    float* u_w     = (float*)take(NE * 4);
    float* i_w     = (float*)take(NE * 4);
    float* normAcc = (float*)take(256);
    int*   csU     = (int*)take((size_t)NCH * NE * 4);
    int*   csI     = (int*)take((size_t)NCH * NE * 4);
    float* csS     = (float*)take((size_t)NCH * NE * 4);  // reused as csA
    int2*  pairs   = (int2*)take((size_t)nnz * 8);
    size_t fixedEnd = off;

    int hb = 256;
    while (hb > 8 && fixedEnd + 3 * (size_t)hb * NE * 4 + 4096 > ws_size) hb >>= 1;
    int spc = hb / NCH;  // slices per chunk (hb is a power of two >= 8)
    int*   sliceU = (int*)take((size_t)hb * NE * 4);
    int*   sliceI = (int*)take((size_t)hb * NE * 4);
    float* sliceS = (float*)take((size_t)hb * NE * 4);  // reused as sliceA

    hipMemsetAsync(normAcc, 0, 256, stream);

    int nb = (nnz + 255) / 256;
    if (nb > 8192) nb = 8192;

    // popularity + counts
    k_hist3<<<hb, HT, 0, stream>>>(ui, ii, vals, nnz, sliceU, sliceI, sliceS);
    k_chunksum3<<<dim3(32, NCH), 256, 0, stream>>>(sliceU, sliceI, sliceS, spc, csU, csI, csS);
    k_final3<<<32, 256, 0, stream>>>(csU, csI, csS, cntU, cntI, popI, normAcc);
    k_scale<<<32, 256, 0, stream>>>(popI, normAcc, 0);

    // user activity (reuses sliceS / csS)
    k_acthist<<<hb, HT, 0, stream>>>(ui, ii, vals, nnz, popI, sliceS);
    k_actchunk<<<dim3(32, NCH), 256, 0, stream>>>(sliceS, spc, csS);
    k_actfinal<<<32, 256, 0, stream>>>(csS, actU, normAcc);
    k_scale<<<32, 256, 0, stream>>>(actU, normAcc, 1);

    // counting-sort offsets for both tables
    k_scan2<<<2, 256, 0, stream>>>(cntU, cntI, ptrU, ptrI);
    k_colscanB<<<dim3(32, 2), 256, 0, stream>>>(csU, csI, ptrU, ptrI);
    k_colscanC<<<dim3(32, NCH, 2), 256, 0, stream>>>(sliceU, sliceI, csU, csI, spc);

    // users
    k_scatter<<<hb, HT, 0, stream>>>(ui, ii, vals, nnz, sliceU, pairs);
    k_rows<<<NE, RT, 0, stream>>>(ptrU, pairs, actU, u_w);
    // items (pairs reused)
    k_scatter<<<hb, HT, 0, stream>>>(ii, ui, vals, nnz, sliceI, pairs);
    k_rows<<<NE, RT, 0, stream>>>(ptrI, pairs, popI, i_w);

    k_out<<<nb, 256, 0, stream>>>(ui, ii, vals, nnz, u_w, i_w, out);
}

// Round 4
// 354.934 us; speedup vs baseline: 2.3727x; 1.0185x over previous
//
#include <hip/hip_runtime.h>
#include <math.h>

#define NE 8192   // num_users == num_items
#define HT 1024   // histogram/scatter block threads
#define NCH 8     // slice chunks for two-level colscan/reduce
#define RWAVES 4  // rows (waves) per k_rows block

// db3 analysis filters, reversed (cross-correlation of reversed filter == convolution)
__device__ __constant__ float LO_R[6] = {
    0.3326705529509569f, 0.8068915093133388f, 0.4598775021193313f,
    -0.13501102001039084f, -0.08544127388224149f, 0.035226291882100656f};
__device__ __constant__ float HI_R[6] = {
    0.035226291882100656f, 0.08544127388224149f, -0.13501102001039084f,
    -0.4598775021193313f, 0.8068915093133388f, -0.3326705529509569f};

// 256-thread block reduce; valid on thread 0.
__device__ __forceinline__ float blockReduceSum(float v, float* red) {
    #pragma unroll
    for (int off = 32; off > 0; off >>= 1) v += __shfl_down(v, off);
    int lane = threadIdx.x & 63, wid = threadIdx.x >> 6;
    if (lane == 0) red[wid] = v;
    __syncthreads();
    float r = 0.f;
    if (threadIdx.x == 0) {
        int nw = blockDim.x >> 6;
        for (int i = 0; i < nw; ++i) r += red[i];
    }
    return r;
}

// (lo,hi) output pair k=2g, 2g+1 from padded input groups a=X4[g], b=X4[g+1]
__device__ __forceinline__ void conv_pair(float4 a, float4 b,
                                          float& lo0, float& hi0,
                                          float& lo1, float& hi1) {
    lo0 = a.x * LO_R[0]; hi0 = a.x * HI_R[0];
    lo0 = fmaf(a.y, LO_R[1], lo0); hi0 = fmaf(a.y, HI_R[1], hi0);
    lo0 = fmaf(a.z, LO_R[2], lo0); hi0 = fmaf(a.z, HI_R[2], hi0);
    lo0 = fmaf(a.w, LO_R[3], lo0); hi0 = fmaf(a.w, HI_R[3], hi0);
    lo0 = fmaf(b.x, LO_R[4], lo0); hi0 = fmaf(b.x, HI_R[4], hi0);
    lo0 = fmaf(b.y, LO_R[5], lo0); hi0 = fmaf(b.y, HI_R[5], hi0);
    lo1 = a.z * LO_R[0]; hi1 = a.z * HI_R[0];
    lo1 = fmaf(a.w, LO_R[1], lo1); hi1 = fmaf(a.w, HI_R[1], hi1);
    lo1 = fmaf(b.x, LO_R[2], lo1); hi1 = fmaf(b.x, HI_R[2], hi1);
    lo1 = fmaf(b.y, LO_R[3], lo1); hi1 = fmaf(b.y, HI_R[3], hi1);
    lo1 = fmaf(b.z, LO_R[4], lo1); hi1 = fmaf(b.z, HI_R[4], hi1);
    lo1 = fmaf(b.w, LO_R[5], lo1); hi1 = fmaf(b.w, HI_R[5], hi1);
}

__global__ __launch_bounds__(HT) void k_hist3(const int* __restrict__ ui,
                                              const int* __restrict__ ii,
                                              const float* __restrict__ v, int nnz,
                                              int* __restrict__ sliceU,
                                              int* __restrict__ sliceI,
                                              float* __restrict__ sliceS) {
    __shared__ int hU[NE];
    __shared__ int hI[NE];
    __shared__ float hS[NE];
    int b = blockIdx.x, tid = threadIdx.x, hb = gridDim.x;
    int4* hU4 = (int4*)hU; int4* hI4 = (int4*)hI; int4* hS4 = (int4*)hS;
    int4 z4 = make_int4(0, 0, 0, 0);
    for (int j = tid; j < NE / 4; j += HT) { hU4[j] = z4; hI4[j] = z4; hS4[j] = z4; }
    __syncthreads();
    int C = (nnz + hb - 1) / hb;
    int beg = b * C, end = min(nnz, beg + C);
    for (int n = beg + tid; n < end; n += HT) {
        atomicAdd(&hU[ui[n]], 1);
        int it = ii[n];
        atomicAdd(&hI[it], 1);
        atomicAdd(&hS[it], v[n]);
    }
    __syncthreads();
    size_t base = (size_t)b * NE;
    int4* sU = (int4*)(sliceU + base); int4* sI = (int4*)(sliceI + base);
    int4* sS = (int4*)(sliceS + base);
    for (int j = tid; j < NE / 4; j += HT) { sU[j] = hU4[j]; sI[j] = hI4[j]; sS[j] = hS4[j]; }
}

__global__ void k_chunksum3(const int* __restrict__ sliceU, const int* __restrict__ sliceI,
                            const float* __restrict__ sliceS, int spc,
                            int* __restrict__ csU, int* __restrict__ csI,
                            float* __restrict__ csS) {
    int i = blockIdx.x * 256 + threadIdx.x;
    int c = blockIdx.y;
    int b0 = c * spc;
    int cu = 0, ci = 0; float sv = 0.f;
    for (int b = b0; b < b0 + spc; ++b) {
        size_t o = (size_t)b * NE + i;
        cu += sliceU[o]; ci += sliceI[o]; sv += sliceS[o];
    }
    size_t oc = (size_t)c * NE + i;
    csU[oc] = cu; csI[oc] = ci; csS[oc] = sv;
}

__global__ void k_final3(const int* __restrict__ csU, const int* __restrict__ csI,
                         const float* __restrict__ csS,
                         int* cntU, int* cntI, float* popraw, float* normAcc) {
    __shared__ float red[4];
    int i = blockIdx.x * 256 + threadIdx.x;
    int cu = 0, ci = 0; float sv = 0.f;
    #pragma unroll
    for (int c = 0; c < NCH; ++c) {
        size_t o = (size_t)c * NE + i;
        cu += csU[o]; ci += csI[o]; sv += csS[o];
    }
    cntU[i] = cu; cntI[i] = ci;
    float p = log1pf((float)ci) * sv;
    popraw[i] = p;
    float s = blockReduceSum(p * p, red);
    if (threadIdx.x == 0) atomicAdd(&normAcc[0], s);
}

__global__ void k_scan2(const int* __restrict__ cntU, const int* __restrict__ cntI,
                        int* ptrU, int* ptrI) {
    __shared__ int sums[256];
    const int* cnt = blockIdx.x ? cntI : cntU;
    int* ptr = blockIdx.x ? ptrI : ptrU;
    int tid = threadIdx.x;
    int base = tid * 32;
    int local[32];
    int s = 0;
    #pragma unroll
    for (int j = 0; j < 32; ++j) { local[j] = cnt[base + j]; s += local[j]; }
    sums[tid] = s;
    __syncthreads();
    for (int off = 1; off < 256; off <<= 1) {
        int t = (tid >= off) ? sums[tid - off] : 0;
        __syncthreads();
        sums[tid] += t;
        __syncthreads();
    }
    int run = (tid > 0) ? sums[tid - 1] : 0;
    #pragma unroll
    for (int j = 0; j < 32; ++j) { ptr[base + j] = run; run += local[j]; }
    if (tid == 255) ptr[NE] = run;
}

__global__ void k_colscanB(int* csU, int* csI,
                           const int* __restrict__ ptrU, const int* __restrict__ ptrI) {
    int i = blockIdx.x * 256 + threadIdx.x;
    int* cs = blockIdx.y ? csI : csU;
    const int* ptr = blockIdx.y ? ptrI : ptrU;
    int run = ptr[i];
    #pragma unroll
    for (int c = 0; c < NCH; ++c) {
        size_t o = (size_t)c * NE + i;
        int t = cs[o]; cs[o] = run; run += t;
    }
}

__global__ void k_colscanC(int* sliceU, int* sliceI,
                           const int* __restrict__ csU, const int* __restrict__ csI, int spc) {
    int i = blockIdx.x * 256 + threadIdx.x;
    int c = blockIdx.y;
    int* slice = blockIdx.z ? sliceI : sliceU;
    const int* cs = blockIdx.z ? csI : csU;
    int run = cs[(size_t)c * NE + i];
    int b0 = c * spc;
    for (int b = b0; b < b0 + spc; ++b) {
        size_t o = (size_t)b * NE + i;
        int t = slice[o]; slice[o] = run; run += t;
    }
}

// Fused: both counting-sort scatters + user-activity histogram (one nnz pass).
__global__ __launch_bounds__(HT) void k_scatter2(const int* __restrict__ ui,
                                                 const int* __restrict__ ii,
                                                 const float* __restrict__ v, int nnz,
                                                 const int* __restrict__ sliceU,
                                                 const int* __restrict__ sliceI,
                                                 const float* __restrict__ popraw,
                                                 const float* __restrict__ normAcc,
                                                 int2* __restrict__ pairsU,
                                                 int2* __restrict__ pairsI,
                                                 float* __restrict__ sliceA) {
    __shared__ int curU[NE];
    __shared__ int curI[NE];
    __shared__ float hA[NE];
    int b = blockIdx.x, tid = threadIdx.x, hb = gridDim.x;
    const int4* sU = (const int4*)(sliceU + (size_t)b * NE);
    const int4* sI = (const int4*)(sliceI + (size_t)b * NE);
    int4* cU4 = (int4*)curU; int4* cI4 = (int4*)curI;
    float4* hA4 = (float4*)hA;
    float4 zf = make_float4(0.f, 0.f, 0.f, 0.f);
    for (int j = tid; j < NE / 4; j += HT) { cU4[j] = sU[j]; cI4[j] = sI[j]; hA4[j] = zf; }
    __syncthreads();
    float rs0 = 1.f / (sqrtf(normAcc[0]) + 1e-8f);
    int C = (nnz + hb - 1) / hb;
    int beg = b * C, end = min(nnz, beg + C);
    for (int n = beg + tid; n < end; n += HT) {
        int u = ui[n], it = ii[n];
        float val = v[n];
        atomicAdd(&hA[u], val / log1pf(popraw[it] * rs0 + 1e-8f));
        int pU = atomicAdd(&curU[u], 1);
        pairsU[pU] = make_int2(it, __float_as_int(val));
        int pI = atomicAdd(&curI[it], 1);
        pairsI[pI] = make_int2(u, __float_as_int(val));
    }
    __syncthreads();
    float4* sA = (float4*)(sliceA + (size_t)b * NE);
    for (int j = tid; j < NE / 4; j += HT) sA[j] = hA4[j];
}

__global__ void k_actchunk(const float* __restrict__ sliceA, int spc, float* __restrict__ csA) {
    int i = blockIdx.x * 256 + threadIdx.x;
    int c = blockIdx.y;
    int b0 = c * spc;
    float a = 0.f;
    for (int b = b0; b < b0 + spc; ++b) a += sliceA[(size_t)b * NE + i];
    csA[(size_t)c * NE + i] = a;
}

__global__ void k_actfinal(const float* __restrict__ csA, float* act, float* normAcc) {
    __shared__ float red[4];
    int i = blockIdx.x * 256 + threadIdx.x;
    float a = 0.f;
    #pragma unroll
    for (int c = 0; c < NCH; ++c) a += csA[(size_t)c * NE + i];
    act[i] = a;
    float s = blockReduceSum(a * a, red);
    if (threadIdx.x == 0) atomicAdd(&normAcc[1], s);
}

// One row per WAVE (4 rows per 256-thread block). Level 1 sparse-scattered
// into lo1 (A) / hi1 (B); levels 2-3 dense; lo3 only summed.
// raw[] is the unnormalized per-row scale source; sc = 1 + raw[r]/(||raw||+1e-8).
__global__ __launch_bounds__(64 * RWAVES) void k_rows(const int* __restrict__ ptr,
                                                      const int2* __restrict__ pairs,
                                                      const float* __restrict__ raw,
                                                      const float* __restrict__ normAcc,
                                                      int slot,
                                                      float* __restrict__ w_out) {
    __shared__ __align__(16) float A[RWAVES][4112];  // lo1 at A[4+k], k<4098
    __shared__ __align__(16) float B[RWAVES][4112];  // hi1, then lo2 at B[4+k], k<2051
    int w = threadIdx.x >> 6, lane = threadIdx.x & 63;
    int r = blockIdx.x * RWAVES + w;
    float* Aw = A[w];
    float* Bw = B[w];
    float4* A4 = (float4*)Aw;
    float4* B4 = (float4*)Bw;
    float2* B2 = (float2*)Bw;
    const float4 z4 = make_float4(0.f, 0.f, 0.f, 0.f);

    for (int j = lane; j < 1028; j += 64) { A4[j] = z4; B4[j] = z4; }
    __syncthreads();

    int beg = ptr[r], end = ptr[r + 1];
    for (int n = beg + lane; n < end; n += 64) {
        int2 pr = pairs[n];
        float v = __int_as_float(pr.y);
        int p = pr.x;
        int par = p & 1;
        int kb = (p >> 1) + 4;
        float l0 = par ? LO_R[5] : LO_R[4], l1 = par ? LO_R[3] : LO_R[2], l2 = par ? LO_R[1] : LO_R[0];
        float h0 = par ? HI_R[5] : HI_R[4], h1 = par ? HI_R[3] : HI_R[2], h2 = par ? HI_R[1] : HI_R[0];
        atomicAdd(&Aw[kb],     v * l0);
        atomicAdd(&Aw[kb + 1], v * l1);
        atomicAdd(&Aw[kb + 2], v * l2);
        atomicAdd(&Bw[kb],     v * h0);
        atomicAdd(&Bw[kb + 1], v * h1);
        atomicAdd(&Bw[kb + 2], v * h2);
    }
    __syncthreads();

    // ||hi1||^2: hi1 = B[4..4101]; groups B4[1..1025] (tail pad zero)
    float s1 = 0.f;
    #pragma unroll 2
    for (int j = 1 + lane; j < 1026; j += 64) {
        float4 h = B4[j];
        s1 += h.x * h.x + h.y * h.y + h.z * h.z + h.w * h.w;
    }
    __syncthreads();  // all hi1 reads done before lo2 overwrites B

    // Level 2: A (lo1, N=4098) -> B (lo2, 2051); hi2 norm in registers.
    // g=1025 computes (lo,hi)=(valid k=2050, zero k=2051) from zero-padded A; safe.
    float s2 = 0.f;
    #pragma unroll 2
    for (int g = lane; g < 1026; g += 64) {
        float4 a = A4[g], b = A4[g + 1];
        float lo0, hi0, lo1, hi1;
        conv_pair(a, b, lo0, hi0, lo1, hi1);
        B2[2 + g] = make_float2(lo0, lo1);
        s2 += hi0 * hi0 + hi1 * hi1;
    }
    if (lane < 2) B2[1028 + lane] = make_float2(0.f, 0.f);  // zero B[2056..2059]
    __syncthreads();

    // Level 3: B (lo2, N=2051) -> registers (1028 outputs = 514 full pairs)
    float s3 = 0.f, ls = 0.f;
    #pragma unroll 2
    for (int g = lane; g < 514; g += 64) {
        float4 a = B4[g], b = B4[g + 1];
        float lo0, hi0, lo1, hi1;
        conv_pair(a, b, lo0, hi0, lo1, hi1);
        ls += lo0 + lo1;
        s3 += hi0 * hi0 + hi1 * hi1;
    }

    #pragma unroll
    for (int off = 32; off > 0; off >>= 1) {
        s1 += __shfl_down(s1, off);
        s2 += __shfl_down(s2, off);
        s3 += __shfl_down(s3, off);
        ls += __shfl_down(ls, off);
    }
    if (lane == 0) {
        float rs = 1.f / (sqrtf(normAcc[slot]) + 1e-8f);
        float sc = 1.f + raw[r] * rs;
        float high = (sqrtf(s1) + sqrtf(s2) + sqrtf(s3)) * sc;
        float low = ls * (1.f / 1028.f) * sc;
        float a1 = fmaxf(low, 1e-6f);
        float a2 = fmaxf(high, 1e-6f);
        w_out[r] = a1 / (a1 + a2);
    }
}

__global__ void k_out(const int* __restrict__ ui, const int* __restrict__ ii,
                      const float* __restrict__ v, int nnz,
                      const float* __restrict__ u_w, const float* __restrict__ i_w,
                      float* __restrict__ out) {
    int idx = blockIdx.x * blockDim.x + threadIdx.x;
    int stride = gridDim.x * blockDim.x;
    for (int n = idx; n < nnz; n += stride) {
        float val = v[n];
        float wu = u_w[ui[n]], wi = i_w[ii[n]];
        float wun = 1.f - wu, win = 1.f - wi;
        out[n] = val * wu * wi;
        out[(size_t)nnz + n] = val * wun * win;
        out[2 * (size_t)nnz + n] = val * wu * win;
        out[3 * (size_t)nnz + n] = val * wun * wi;
    }
}

extern "C" void kernel_launch(void* const* d_in, const int* in_sizes, int n_in,
                              void* d_out, int out_size, void* d_ws, size_t ws_size,
                              hipStream_t stream) {
    const int* ui = (const int*)d_in[0];
    const int* ii = (const int*)d_in[1];
    const float* vals = (const float*)d_in[2];
    int nnz = in_sizes[0];
    float* out = (float*)d_out;

    char* ws = (char*)d_ws;
    size_t off = 0;
    auto take = [&](size_t bytes) -> char* {
        char* p = ws + off;
        off = (off + bytes + 255) & ~(size_t)255;
        return p;
    };

    int*   cntU    = (int*)take(NE * 4);
    int*   cntI    = (int*)take(NE * 4);
    float* popraw  = (float*)take(NE * 4);
    float* actraw  = (float*)take(NE * 4);
    int*   ptrU    = (int*)take((NE + 1) * 4);
    int*   ptrI    = (int*)take((NE + 1) * 4);
    float* u_w     = (float*)take(NE * 4);
    float* i_w     = (float*)take(NE * 4);
    float* normAcc = (float*)take(256);
    int*   csU     = (int*)take((size_t)NCH * NE * 4);
    int*   csI     = (int*)take((size_t)NCH * NE * 4);
    float* csS     = (float*)take((size_t)NCH * NE * 4);  // reused as csA
    int2*  pairsU  = (int2*)take((size_t)nnz * 8);
    int2*  pairsI  = (int2*)take((size_t)nnz * 8);
    size_t fixedEnd = off;

    int hb = 256;
    while (hb > 8 && fixedEnd + 3 * (size_t)hb * NE * 4 + 4096 > ws_size) hb >>= 1;
    int spc = hb / NCH;
    int*   sliceU = (int*)take((size_t)hb * NE * 4);
    int*   sliceI = (int*)take((size_t)hb * NE * 4);
    float* sliceS = (float*)take((size_t)hb * NE * 4);  // reused as sliceA

    hipMemsetAsync(normAcc, 0, 256, stream);

    int nb = (nnz + 255) / 256;
    if (nb > 2048) nb = 2048;

    // popularity + counts
    k_hist3<<<hb, HT, 0, stream>>>(ui, ii, vals, nnz, sliceU, sliceI, sliceS);
    k_chunksum3<<<dim3(32, NCH), 256, 0, stream>>>(sliceU, sliceI, sliceS, spc, csU, csI, csS);
    k_final3<<<32, 256, 0, stream>>>(csU, csI, csS, cntU, cntI, popraw, normAcc);

    // counting-sort offsets for both tables
    k_scan2<<<2, 256, 0, stream>>>(cntU, cntI, ptrU, ptrI);
    k_colscanB<<<dim3(32, 2), 256, 0, stream>>>(csU, csI, ptrU, ptrI);
    k_colscanC<<<dim3(32, NCH, 2), 256, 0, stream>>>(sliceU, sliceI, csU, csI, spc);

    // one fused pass: both scatters + activity histogram partials
    k_scatter2<<<hb, HT, 0, stream>>>(ui, ii, vals, nnz, sliceU, sliceI,
                                      popraw, normAcc, pairsU, pairsI, sliceS);

    // item rows (needs pairsI + popraw + normAcc[0])
    k_rows<<<NE / RWAVES, 64 * RWAVES, 0, stream>>>(ptrI, pairsI, popraw, normAcc, 0, i_w);

    // finish activity, then user rows
    k_actchunk<<<dim3(32, NCH), 256, 0, stream>>>(sliceS, spc, csS);
    k_actfinal<<<32, 256, 0, stream>>>(csS, actraw, normAcc);
    k_rows<<<NE / RWAVES, 64 * RWAVES, 0, stream>>>(ptrU, pairsU, actraw, normAcc, 1, u_w);

    k_out<<<nb, 256, 0, stream>>>(ui, ii, vals, nnz, u_w, i_w, out);
}

// Round 5
// 345.737 us; speedup vs baseline: 2.4358x; 1.0266x over previous
//
#include <hip/hip_runtime.h>
#include <math.h>

#define NE 8192   // num_users == num_items
#define HT 1024   // histogram/scatter block threads
#define NCH 8     // slice chunks for two-level colscan/reduce

// db3 analysis filters, reversed (cross-correlation of reversed filter == convolution)
__device__ __constant__ float LO_R[6] = {
    0.3326705529509569f, 0.8068915093133388f, 0.4598775021193313f,
    -0.13501102001039084f, -0.08544127388224149f, 0.035226291882100656f};
__device__ __constant__ float HI_R[6] = {
    0.035226291882100656f, 0.08544127388224149f, -0.13501102001039084f,
    -0.4598775021193313f, 0.8068915093133388f, -0.3326705529509569f};

// 256-thread block reduce; valid on thread 0.
__device__ __forceinline__ float blockReduceSum(float v, float* red) {
    #pragma unroll
    for (int off = 32; off > 0; off >>= 1) v += __shfl_down(v, off);
    int lane = threadIdx.x & 63, wid = threadIdx.x >> 6;
    if (lane == 0) red[wid] = v;
    __syncthreads();
    float r = 0.f;
    if (threadIdx.x == 0) {
        int nw = blockDim.x >> 6;
        for (int i = 0; i < nw; ++i) r += red[i];
    }
    return r;
}

// (lo,hi) output pair k=2g, 2g+1 from padded input groups a=X4[g], b=X4[g+1]
__device__ __forceinline__ void conv_pair(float4 a, float4 b,
                                          float& lo0, float& hi0,
                                          float& lo1, float& hi1) {
    lo0 = a.x * LO_R[0]; hi0 = a.x * HI_R[0];
    lo0 = fmaf(a.y, LO_R[1], lo0); hi0 = fmaf(a.y, HI_R[1], hi0);
    lo0 = fmaf(a.z, LO_R[2], lo0); hi0 = fmaf(a.z, HI_R[2], hi0);
    lo0 = fmaf(a.w, LO_R[3], lo0); hi0 = fmaf(a.w, HI_R[3], hi0);
    lo0 = fmaf(b.x, LO_R[4], lo0); hi0 = fmaf(b.x, HI_R[4], hi0);
    lo0 = fmaf(b.y, LO_R[5], lo0); hi0 = fmaf(b.y, HI_R[5], hi0);
    lo1 = a.z * LO_R[0]; hi1 = a.z * HI_R[0];
    lo1 = fmaf(a.w, LO_R[1], lo1); hi1 = fmaf(a.w, HI_R[1], hi1);
    lo1 = fmaf(b.x, LO_R[2], lo1); hi1 = fmaf(b.x, HI_R[2], hi1);
    lo1 = fmaf(b.y, LO_R[3], lo1); hi1 = fmaf(b.y, HI_R[3], hi1);
    lo1 = fmaf(b.z, LO_R[4], lo1); hi1 = fmaf(b.z, HI_R[4], hi1);
    lo1 = fmaf(b.w, LO_R[5], lo1); hi1 = fmaf(b.w, HI_R[5], hi1);
}

__global__ __launch_bounds__(HT) void k_hist3(const int* __restrict__ ui,
                                              const int* __restrict__ ii,
                                              const float* __restrict__ v, int nnz,
                                              int* __restrict__ sliceU,
                                              int* __restrict__ sliceI,
                                              float* __restrict__ sliceS) {
    __shared__ int hU[NE];
    __shared__ int hI[NE];
    __shared__ float hS[NE];
    int b = blockIdx.x, tid = threadIdx.x, hb = gridDim.x;
    int4* hU4 = (int4*)hU; int4* hI4 = (int4*)hI; int4* hS4 = (int4*)hS;
    int4 z4 = make_int4(0, 0, 0, 0);
    for (int j = tid; j < NE / 4; j += HT) { hU4[j] = z4; hI4[j] = z4; hS4[j] = z4; }
    __syncthreads();
    int C = (nnz + hb - 1) / hb;
    int beg = b * C, end = min(nnz, beg + C);
    for (int n = beg + tid; n < end; n += HT) {
        atomicAdd(&hU[ui[n]], 1);
        int it = ii[n];
        atomicAdd(&hI[it], 1);
        atomicAdd(&hS[it], v[n]);
    }
    __syncthreads();
    size_t base = (size_t)b * NE;
    int4* sU = (int4*)(sliceU + base); int4* sI = (int4*)(sliceI + base);
    int4* sS = (int4*)(sliceS + base);
    for (int j = tid; j < NE / 4; j += HT) { sU[j] = hU4[j]; sI[j] = hI4[j]; sS[j] = hS4[j]; }
}

__global__ void k_chunksum3(const int* __restrict__ sliceU, const int* __restrict__ sliceI,
                            const float* __restrict__ sliceS, int spc,
                            int* __restrict__ csU, int* __restrict__ csI,
                            float* __restrict__ csS) {
    int i = blockIdx.x * 256 + threadIdx.x;
    int c = blockIdx.y;
    int b0 = c * spc;
    int cu = 0, ci = 0; float sv = 0.f;
    for (int b = b0; b < b0 + spc; ++b) {
        size_t o = (size_t)b * NE + i;
        cu += sliceU[o]; ci += sliceI[o]; sv += sliceS[o];
    }
    size_t oc = (size_t)c * NE + i;
    csU[oc] = cu; csI[oc] = ci; csS[oc] = sv;
}

__global__ void k_final3(const int* __restrict__ csU, const int* __restrict__ csI,
                         const float* __restrict__ csS,
                         int* cntU, int* cntI, float* popraw, float* normAcc) {
    __shared__ float red[4];
    int i = blockIdx.x * 256 + threadIdx.x;
    int cu = 0, ci = 0; float sv = 0.f;
    #pragma unroll
    for (int c = 0; c < NCH; ++c) {
        size_t o = (size_t)c * NE + i;
        cu += csU[o]; ci += csI[o]; sv += csS[o];
    }
    cntU[i] = cu; cntI[i] = ci;
    float p = log1pf((float)ci) * sv;
    popraw[i] = p;
    float s = blockReduceSum(p * p, red);
    if (threadIdx.x == 0) atomicAdd(&normAcc[0], s);
}

__global__ void k_scan2(const int* __restrict__ cntU, const int* __restrict__ cntI,
                        int* ptrU, int* ptrI) {
    __shared__ int sums[256];
    const int* cnt = blockIdx.x ? cntI : cntU;
    int* ptr = blockIdx.x ? ptrI : ptrU;
    int tid = threadIdx.x;
    int base = tid * 32;
    int local[32];
    int s = 0;
    #pragma unroll
    for (int j = 0; j < 32; ++j) { local[j] = cnt[base + j]; s += local[j]; }
    sums[tid] = s;
    __syncthreads();
    for (int off = 1; off < 256; off <<= 1) {
        int t = (tid >= off) ? sums[tid - off] : 0;
        __syncthreads();
        sums[tid] += t;
        __syncthreads();
    }
    int run = (tid > 0) ? sums[tid - 1] : 0;
    #pragma unroll
    for (int j = 0; j < 32; ++j) { ptr[base + j] = run; run += local[j]; }
    if (tid == 255) ptr[NE] = run;
}

__global__ void k_colscanB(int* csU, int* csI,
                           const int* __restrict__ ptrU, const int* __restrict__ ptrI) {
    int i = blockIdx.x * 256 + threadIdx.x;
    int* cs = blockIdx.y ? csI : csU;
    const int* ptr = blockIdx.y ? ptrI : ptrU;
    int run = ptr[i];
    #pragma unroll
    for (int c = 0; c < NCH; ++c) {
        size_t o = (size_t)c * NE + i;
        int t = cs[o]; cs[o] = run; run += t;
    }
}

__global__ void k_colscanC(int* sliceU, int* sliceI,
                           const int* __restrict__ csU, const int* __restrict__ csI, int spc) {
    int i = blockIdx.x * 256 + threadIdx.x;
    int c = blockIdx.y;
    int* slice = blockIdx.z ? sliceI : sliceU;
    const int* cs = blockIdx.z ? csI : csU;
    int run = cs[(size_t)c * NE + i];
    int b0 = c * spc;
    for (int b = b0; b < b0 + spc; ++b) {
        size_t o = (size_t)b * NE + i;
        int t = slice[o]; slice[o] = run; run += t;
    }
}

// Fused: both counting-sort scatters + user-activity histogram (one nnz pass).
__global__ __launch_bounds__(HT) void k_scatter2(const int* __restrict__ ui,
                                                 const int* __restrict__ ii,
                                                 const float* __restrict__ v, int nnz,
                                                 const int* __restrict__ sliceU,
                                                 const int* __restrict__ sliceI,
                                                 const float* __restrict__ popraw,
                                                 const float* __restrict__ normAcc,
                                                 int2* __restrict__ pairsU,
                                                 int2* __restrict__ pairsI,
                                                 float* __restrict__ sliceA) {
    __shared__ int curU[NE];
    __shared__ int curI[NE];
    __shared__ float hA[NE];
    int b = blockIdx.x, tid = threadIdx.x, hb = gridDim.x;
    const int4* sU = (const int4*)(sliceU + (size_t)b * NE);
    const int4* sI = (const int4*)(sliceI + (size_t)b * NE);
    int4* cU4 = (int4*)curU; int4* cI4 = (int4*)curI;
    float4* hA4 = (float4*)hA;
    float4 zf = make_float4(0.f, 0.f, 0.f, 0.f);
    for (int j = tid; j < NE / 4; j += HT) { cU4[j] = sU[j]; cI4[j] = sI[j]; hA4[j] = zf; }
    __syncthreads();
    float rs0 = 1.f / (sqrtf(normAcc[0]) + 1e-8f);
    int C = (nnz + hb - 1) / hb;
    int beg = b * C, end = min(nnz, beg + C);
    for (int n = beg + tid; n < end; n += HT) {
        int u = ui[n], it = ii[n];
        float val = v[n];
        atomicAdd(&hA[u], val / log1pf(popraw[it] * rs0 + 1e-8f));
        int pU = atomicAdd(&curU[u], 1);
        pairsU[pU] = make_int2(it, __float_as_int(val));
        int pI = atomicAdd(&curI[it], 1);
        pairsI[pI] = make_int2(u, __float_as_int(val));
    }
    __syncthreads();
    float4* sA = (float4*)(sliceA + (size_t)b * NE);
    for (int j = tid; j < NE / 4; j += HT) sA[j] = hA4[j];
}

__global__ void k_actchunk(const float* __restrict__ sliceA, int spc, float* __restrict__ csA) {
    int i = blockIdx.x * 256 + threadIdx.x;
    int c = blockIdx.y;
    int b0 = c * spc;
    float a = 0.f;
    for (int b = b0; b < b0 + spc; ++b) a += sliceA[(size_t)b * NE + i];
    csA[(size_t)c * NE + i] = a;
}

__global__ void k_actfinal(const float* __restrict__ csA, float* act, float* normAcc) {
    __shared__ float red[4];
    int i = blockIdx.x * 256 + threadIdx.x;
    float a = 0.f;
    #pragma unroll
    for (int c = 0; c < NCH; ++c) a += csA[(size_t)c * NE + i];
    act[i] = a;
    float s = blockReduceSum(a * a, red);
    if (threadIdx.x == 0) atomicAdd(&normAcc[1], s);
}

// One row per 64-thread block (one wave). Level 1 sparse-scattered into
// lo1 (A) / hi1 (B); levels 2-3 dense with 4-wide register blocking for ILP.
__global__ __launch_bounds__(64) void k_rows(const int* __restrict__ ptr,
                                             const int2* __restrict__ pairs,
                                             const float* __restrict__ raw,
                                             const float* __restrict__ normAcc,
                                             int slot,
                                             float* __restrict__ w_out) {
    __shared__ __align__(16) float A[4112];  // lo1 at A[4+k], k<4098
    __shared__ __align__(16) float B[4112];  // hi1, then lo2 at B[4+k], k<2051
    int lane = threadIdx.x;
    int r = blockIdx.x;
    float4* A4 = (float4*)A;
    float4* B4 = (float4*)B;
    const float4 z4 = make_float4(0.f, 0.f, 0.f, 0.f);

    for (int j = lane; j < 1028; j += 64) { A4[j] = z4; B4[j] = z4; }
    __syncthreads();

    int beg = ptr[r], end = ptr[r + 1];
    for (int n = beg + lane; n < end; n += 64) {
        int2 pr = pairs[n];
        float v = __int_as_float(pr.y);
        int p = pr.x;
        int par = p & 1;
        int kb = (p >> 1) + 4;
        float l0 = par ? LO_R[5] : LO_R[4], l1 = par ? LO_R[3] : LO_R[2], l2 = par ? LO_R[1] : LO_R[0];
        float h0 = par ? HI_R[5] : HI_R[4], h1 = par ? HI_R[3] : HI_R[2], h2 = par ? HI_R[1] : HI_R[0];
        atomicAdd(&A[kb],     v * l0);
        atomicAdd(&A[kb + 1], v * l1);
        atomicAdd(&A[kb + 2], v * l2);
        atomicAdd(&B[kb],     v * h0);
        atomicAdd(&B[kb + 1], v * h1);
        atomicAdd(&B[kb + 2], v * h2);
    }
    __syncthreads();

    // s1 = ||hi1||^2 over all of B (pads are zero): groups B4[0..1027]
    float s1 = 0.f;
    #pragma unroll
    for (int i = 0; i < 4; ++i) {
        int g = i * 256 + lane * 4;
        float4 h0 = B4[g], h1 = B4[g + 1], h2 = B4[g + 2], h3 = B4[g + 3];
        s1 += h0.x * h0.x + h0.y * h0.y + h0.z * h0.z + h0.w * h0.w;
        s1 += h1.x * h1.x + h1.y * h1.y + h1.z * h1.z + h1.w * h1.w;
        s1 += h2.x * h2.x + h2.y * h2.y + h2.z * h2.z + h2.w * h2.w;
        s1 += h3.x * h3.x + h3.y * h3.y + h3.z * h3.z + h3.w * h3.w;
    }
    if (lane < 4) {
        float4 h = B4[1024 + lane];
        s1 += h.x * h.x + h.y * h.y + h.z * h.z + h.w * h.w;
    }
    __syncthreads();  // all hi1 reads done before lo2 overwrites B

    // Level 2: A (lo1) -> B (lo2), s2 in regs. 4 groups (8 outputs) per lane per iter.
    float s2 = 0.f;
    #pragma unroll
    for (int i = 0; i < 4; ++i) {
        int g0 = i * 256 + lane * 4;
        float4 a0 = A4[g0], a1 = A4[g0 + 1], a2 = A4[g0 + 2], a3 = A4[g0 + 3], a4 = A4[g0 + 4];
        float lo[8], hi[8];
        conv_pair(a0, a1, lo[0], hi[0], lo[1], hi[1]);
        conv_pair(a1, a2, lo[2], hi[2], lo[3], hi[3]);
        conv_pair(a2, a3, lo[4], hi[4], lo[5], hi[5]);
        conv_pair(a3, a4, lo[6], hi[6], lo[7], hi[7]);
        int w = 1 + (g0 >> 1);
        B4[w]     = make_float4(lo[0], lo[1], lo[2], lo[3]);
        B4[w + 1] = make_float4(lo[4], lo[5], lo[6], lo[7]);
        s2 += hi[0] * hi[0] + hi[1] * hi[1] + hi[2] * hi[2] + hi[3] * hi[3];
        s2 += hi[4] * hi[4] + hi[5] * hi[5] + hi[6] * hi[6] + hi[7] * hi[7];
    }
    if (lane < 2) {  // tail groups g = 1024, 1025 -> k = 2048..2051
        int g = 1024 + lane;
        float4 a = A4[g], b = A4[g + 1];
        float lo0, hi0, lo1, hi1;
        conv_pair(a, b, lo0, hi0, lo1, hi1);
        *(float2*)&B[4 + 2 * g] = make_float2(lo0, lo1);
        s2 += hi0 * hi0 + hi1 * hi1;
    }
    if (lane >= 2 && lane < 4) B4[512 + lane] = z4;  // zero stale floats 2056..2063
    __syncthreads();

    // Level 3: B (lo2) -> registers. 514 groups g=0..513.
    float s3 = 0.f, ls = 0.f;
    #pragma unroll
    for (int i = 0; i < 2; ++i) {
        int g0 = i * 256 + lane * 4;
        float4 b0 = B4[g0], b1 = B4[g0 + 1], b2 = B4[g0 + 2], b3 = B4[g0 + 3], b4 = B4[g0 + 4];
        float lo[8], hi[8];
        conv_pair(b0, b1, lo[0], hi[0], lo[1], hi[1]);
        conv_pair(b1, b2, lo[2], hi[2], lo[3], hi[3]);
        conv_pair(b2, b3, lo[4], hi[4], lo[5], hi[5]);
        conv_pair(b3, b4, lo[6], hi[6], lo[7], hi[7]);
        ls += lo[0] + lo[1] + lo[2] + lo[3] + lo[4] + lo[5] + lo[6] + lo[7];
        s3 += hi[0] * hi[0] + hi[1] * hi[1] + hi[2] * hi[2] + hi[3] * hi[3];
        s3 += hi[4] * hi[4] + hi[5] * hi[5] + hi[6] * hi[6] + hi[7] * hi[7];
    }
    if (lane < 2) {  // tail groups g = 512, 513
        int g = 512 + lane;
        float4 a = B4[g], b = B4[g + 1];
        float lo0, hi0, lo1, hi1;
        conv_pair(a, b, lo0, hi0, lo1, hi1);
        ls += lo0 + lo1;
        s3 += hi0 * hi0 + hi1 * hi1;
    }

    #pragma unroll
    for (int off = 32; off > 0; off >>= 1) {
        s1 += __shfl_down(s1, off);
        s2 += __shfl_down(s2, off);
        s3 += __shfl_down(s3, off);
        ls += __shfl_down(ls, off);
    }
    if (lane == 0) {
        float rs = 1.f / (sqrtf(normAcc[slot]) + 1e-8f);
        float sc = 1.f + raw[r] * rs;
        float high = (sqrtf(s1) + sqrtf(s2) + sqrtf(s3)) * sc;
        float low = ls * (1.f / 1028.f) * sc;
        float a1 = fmaxf(low, 1e-6f);
        float a2 = fmaxf(high, 1e-6f);
        w_out[r] = a1 / (a1 + a2);
    }
}

__global__ void k_out(const int* __restrict__ ui, const int* __restrict__ ii,
                      const float* __restrict__ v, int nnz,
                      const float* __restrict__ u_w, const float* __restrict__ i_w,
                      float* __restrict__ out) {
    int idx = blockIdx.x * blockDim.x + threadIdx.x;
    int stride = gridDim.x * blockDim.x;
    for (int n = idx; n < nnz; n += stride) {
        float val = v[n];
        float wu = u_w[ui[n]], wi = i_w[ii[n]];
        float wun = 1.f - wu, win = 1.f - wi;
        out[n] = val * wu * wi;
        out[(size_t)nnz + n] = val * wun * win;
        out[2 * (size_t)nnz + n] = val * wu * win;
        out[3 * (size_t)nnz + n] = val * wun * wi;
    }
}

extern "C" void kernel_launch(void* const* d_in, const int* in_sizes, int n_in,
                              void* d_out, int out_size, void* d_ws, size_t ws_size,
                              hipStream_t stream) {
    const int* ui = (const int*)d_in[0];
    const int* ii = (const int*)d_in[1];
    const float* vals = (const float*)d_in[2];
    int nnz = in_sizes[0];
    float* out = (float*)d_out;

    char* ws = (char*)d_ws;
    size_t off = 0;
    auto take = [&](size_t bytes) -> char* {
        char* p = ws + off;
        off = (off + bytes + 255) & ~(size_t)255;
        return p;
    };

    int*   cntU    = (int*)take(NE * 4);
    int*   cntI    = (int*)take(NE * 4);
    float* popraw  = (float*)take(NE * 4);
    float* actraw  = (float*)take(NE * 4);
    int*   ptrU    = (int*)take((NE + 1) * 4);
    int*   ptrI    = (int*)take((NE + 1) * 4);
    float* u_w     = (float*)take(NE * 4);
    float* i_w     = (float*)take(NE * 4);
    float* normAcc = (float*)take(256);
    int*   csU     = (int*)take((size_t)NCH * NE * 4);
    int*   csI     = (int*)take((size_t)NCH * NE * 4);
    float* csS     = (float*)take((size_t)NCH * NE * 4);  // reused as csA
    int2*  pairsU  = (int2*)take((size_t)nnz * 8);
    int2*  pairsI  = (int2*)take((size_t)nnz * 8);
    size_t fixedEnd = off;

    int hb = 256;
    while (hb > 8 && fixedEnd + 3 * (size_t)hb * NE * 4 + 4096 > ws_size) hb >>= 1;
    int spc = hb / NCH;
    int*   sliceU = (int*)take((size_t)hb * NE * 4);
    int*   sliceI = (int*)take((size_t)hb * NE * 4);
    float* sliceS = (float*)take((size_t)hb * NE * 4);  // reused as sliceA

    hipMemsetAsync(normAcc, 0, 256, stream);

    int nb = (nnz + 255) / 256;
    if (nb > 2048) nb = 2048;

    // popularity + counts
    k_hist3<<<hb, HT, 0, stream>>>(ui, ii, vals, nnz, sliceU, sliceI, sliceS);
    k_chunksum3<<<dim3(32, NCH), 256, 0, stream>>>(sliceU, sliceI, sliceS, spc, csU, csI, csS);
    k_final3<<<32, 256, 0, stream>>>(csU, csI, csS, cntU, cntI, popraw, normAcc);

    // counting-sort offsets for both tables
    k_scan2<<<2, 256, 0, stream>>>(cntU, cntI, ptrU, ptrI);
    k_colscanB<<<dim3(32, 2), 256, 0, stream>>>(csU, csI, ptrU, ptrI);
    k_colscanC<<<dim3(32, NCH, 2), 256, 0, stream>>>(sliceU, sliceI, csU, csI, spc);

    // one fused pass: both scatters + activity histogram partials
    k_scatter2<<<hb, HT, 0, stream>>>(ui, ii, vals, nnz, sliceU, sliceI,
                                      popraw, normAcc, pairsU, pairsI, sliceS);

    // item rows (needs pairsI + popraw + normAcc[0])
    k_rows<<<NE, 64, 0, stream>>>(ptrI, pairsI, popraw, normAcc, 0, i_w);

    // finish activity, then user rows
    k_actchunk<<<dim3(32, NCH), 256, 0, stream>>>(sliceS, spc, csS);
    k_actfinal<<<32, 256, 0, stream>>>(csS, actraw, normAcc);
    k_rows<<<NE, 64, 0, stream>>>(ptrU, pairsU, actraw, normAcc, 1, u_w);

    k_out<<<nb, 256, 0, stream>>>(ui, ii, vals, nnz, u_w, i_w, out);
}

// Round 6
// 339.874 us; speedup vs baseline: 2.4778x; 1.0173x over previous
//
#include <hip/hip_runtime.h>
#include <math.h>

#define NE 8192   // num_users == num_items
#define HT 1024   // histogram/scatter block threads
#define NCH 8     // slice chunks for two-level colscan/reduce

// db3 analysis filters, reversed (cross-correlation of reversed filter == convolution)
__device__ __constant__ float LO_R[6] = {
    0.3326705529509569f, 0.8068915093133388f, 0.4598775021193313f,
    -0.13501102001039084f, -0.08544127388224149f, 0.035226291882100656f};
__device__ __constant__ float HI_R[6] = {
    0.035226291882100656f, 0.08544127388224149f, -0.13501102001039084f,
    -0.4598775021193313f, 0.8068915093133388f, -0.3326705529509569f};

// 256-thread block reduce; valid on thread 0.
__device__ __forceinline__ float blockReduceSum(float v, float* red) {
    #pragma unroll
    for (int off = 32; off > 0; off >>= 1) v += __shfl_down(v, off);
    int lane = threadIdx.x & 63, wid = threadIdx.x >> 6;
    if (lane == 0) red[wid] = v;
    __syncthreads();
    float r = 0.f;
    if (threadIdx.x == 0) {
        int nw = blockDim.x >> 6;
        for (int i = 0; i < nw; ++i) r += red[i];
    }
    return r;
}

// (lo,hi) output pair k=2g, 2g+1 from padded input groups a=X4[g], b=X4[g+1]
__device__ __forceinline__ void conv_pair(float4 a, float4 b,
                                          float& lo0, float& hi0,
                                          float& lo1, float& hi1) {
    lo0 = a.x * LO_R[0]; hi0 = a.x * HI_R[0];
    lo0 = fmaf(a.y, LO_R[1], lo0); hi0 = fmaf(a.y, HI_R[1], hi0);
    lo0 = fmaf(a.z, LO_R[2], lo0); hi0 = fmaf(a.z, HI_R[2], hi0);
    lo0 = fmaf(a.w, LO_R[3], lo0); hi0 = fmaf(a.w, HI_R[3], hi0);
    lo0 = fmaf(b.x, LO_R[4], lo0); hi0 = fmaf(b.x, HI_R[4], hi0);
    lo0 = fmaf(b.y, LO_R[5], lo0); hi0 = fmaf(b.y, HI_R[5], hi0);
    lo1 = a.z * LO_R[0]; hi1 = a.z * HI_R[0];
    lo1 = fmaf(a.w, LO_R[1], lo1); hi1 = fmaf(a.w, HI_R[1], hi1);
    lo1 = fmaf(b.x, LO_R[2], lo1); hi1 = fmaf(b.x, HI_R[2], hi1);
    lo1 = fmaf(b.y, LO_R[3], lo1); hi1 = fmaf(b.y, HI_R[3], hi1);
    lo1 = fmaf(b.z, LO_R[4], lo1); hi1 = fmaf(b.z, HI_R[4], hi1);
    lo1 = fmaf(b.w, LO_R[5], lo1); hi1 = fmaf(b.w, HI_R[5], hi1);
}

__global__ __launch_bounds__(HT) void k_hist3(const int* __restrict__ ui,
                                              const int* __restrict__ ii,
                                              const float* __restrict__ v, int nnz,
                                              int* __restrict__ sliceU,
                                              int* __restrict__ sliceI,
                                              float* __restrict__ sliceS) {
    __shared__ int hU[NE];
    __shared__ int hI[NE];
    __shared__ float hS[NE];
    int b = blockIdx.x, tid = threadIdx.x, hb = gridDim.x;
    int4* hU4 = (int4*)hU; int4* hI4 = (int4*)hI; int4* hS4 = (int4*)hS;
    int4 z4 = make_int4(0, 0, 0, 0);
    for (int j = tid; j < NE / 4; j += HT) { hU4[j] = z4; hI4[j] = z4; hS4[j] = z4; }
    __syncthreads();
    int C = (nnz + hb - 1) / hb;
    int beg = b * C, end = min(nnz, beg + C);
    for (int n = beg + tid; n < end; n += HT) {
        atomicAdd(&hU[ui[n]], 1);
        int it = ii[n];
        atomicAdd(&hI[it], 1);
        atomicAdd(&hS[it], v[n]);
    }
    __syncthreads();
    size_t base = (size_t)b * NE;
    int4* sU = (int4*)(sliceU + base); int4* sI = (int4*)(sliceI + base);
    int4* sS = (int4*)(sliceS + base);
    for (int j = tid; j < NE / 4; j += HT) { sU[j] = hU4[j]; sI[j] = hI4[j]; sS[j] = hS4[j]; }
}

__global__ void k_chunksum3(const int* __restrict__ sliceU, const int* __restrict__ sliceI,
                            const float* __restrict__ sliceS, int spc,
                            int* __restrict__ csU, int* __restrict__ csI,
                            float* __restrict__ csS) {
    int i = blockIdx.x * 256 + threadIdx.x;
    int c = blockIdx.y;
    int b0 = c * spc;
    int cu = 0, ci = 0; float sv = 0.f;
    for (int b = b0; b < b0 + spc; ++b) {
        size_t o = (size_t)b * NE + i;
        cu += sliceU[o]; ci += sliceI[o]; sv += sliceS[o];
    }
    size_t oc = (size_t)c * NE + i;
    csU[oc] = cu; csI[oc] = ci; csS[oc] = sv;
}

__global__ void k_final3(const int* __restrict__ csU, const int* __restrict__ csI,
                         const float* __restrict__ csS,
                         int* cntU, int* cntI, float* popraw, float* normAcc) {
    __shared__ float red[4];
    int i = blockIdx.x * 256 + threadIdx.x;
    int cu = 0, ci = 0; float sv = 0.f;
    #pragma unroll
    for (int c = 0; c < NCH; ++c) {
        size_t o = (size_t)c * NE + i;
        cu += csU[o]; ci += csI[o]; sv += csS[o];
    }
    cntU[i] = cu; cntI[i] = ci;
    float p = log1pf((float)ci) * sv;
    popraw[i] = p;
    float s = blockReduceSum(p * p, red);
    if (threadIdx.x == 0) atomicAdd(&normAcc[0], s);
}

__global__ void k_scan2(const int* __restrict__ cntU, const int* __restrict__ cntI,
                        int* ptrU, int* ptrI) {
    __shared__ int sums[256];
    const int* cnt = blockIdx.x ? cntI : cntU;
    int* ptr = blockIdx.x ? ptrI : ptrU;
    int tid = threadIdx.x;
    int base = tid * 32;
    int local[32];
    int s = 0;
    #pragma unroll
    for (int j = 0; j < 32; ++j) { local[j] = cnt[base + j]; s += local[j]; }
    sums[tid] = s;
    __syncthreads();
    for (int off = 1; off < 256; off <<= 1) {
        int t = (tid >= off) ? sums[tid - off] : 0;
        __syncthreads();
        sums[tid] += t;
        __syncthreads();
    }
    int run = (tid > 0) ? sums[tid - 1] : 0;
    #pragma unroll
    for (int j = 0; j < 32; ++j) { ptr[base + j] = run; run += local[j]; }
    if (tid == 255) ptr[NE] = run;
}

__global__ void k_colscanB(int* csU, int* csI,
                           const int* __restrict__ ptrU, const int* __restrict__ ptrI) {
    int i = blockIdx.x * 256 + threadIdx.x;
    int* cs = blockIdx.y ? csI : csU;
    const int* ptr = blockIdx.y ? ptrI : ptrU;
    int run = ptr[i];
    #pragma unroll
    for (int c = 0; c < NCH; ++c) {
        size_t o = (size_t)c * NE + i;
        int t = cs[o]; cs[o] = run; run += t;
    }
}

__global__ void k_colscanC(int* sliceU, int* sliceI,
                           const int* __restrict__ csU, const int* __restrict__ csI, int spc) {
    int i = blockIdx.x * 256 + threadIdx.x;
    int c = blockIdx.y;
    int* slice = blockIdx.z ? sliceI : sliceU;
    const int* cs = blockIdx.z ? csI : csU;
    int run = cs[(size_t)c * NE + i];
    int b0 = c * spc;
    for (int b = b0; b < b0 + spc; ++b) {
        size_t o = (size_t)b * NE + i;
        int t = slice[o]; slice[o] = run; run += t;
    }
}

// Fused: both counting-sort scatters + user-activity histogram (one nnz pass).
__global__ __launch_bounds__(HT) void k_scatter2(const int* __restrict__ ui,
                                                 const int* __restrict__ ii,
                                                 const float* __restrict__ v, int nnz,
                                                 const int* __restrict__ sliceU,
                                                 const int* __restrict__ sliceI,
                                                 const float* __restrict__ popraw,
                                                 const float* __restrict__ normAcc,
                                                 int2* __restrict__ pairsU,
                                                 int2* __restrict__ pairsI,
                                                 float* __restrict__ sliceA) {
    __shared__ int curU[NE];
    __shared__ int curI[NE];
    __shared__ float hA[NE];
    int b = blockIdx.x, tid = threadIdx.x, hb = gridDim.x;
    const int4* sU = (const int4*)(sliceU + (size_t)b * NE);
    const int4* sI = (const int4*)(sliceI + (size_t)b * NE);
    int4* cU4 = (int4*)curU; int4* cI4 = (int4*)curI;
    float4* hA4 = (float4*)hA;
    float4 zf = make_float4(0.f, 0.f, 0.f, 0.f);
    for (int j = tid; j < NE / 4; j += HT) { cU4[j] = sU[j]; cI4[j] = sI[j]; hA4[j] = zf; }
    __syncthreads();
    float rs0 = 1.f / (sqrtf(normAcc[0]) + 1e-8f);
    int C = (nnz + hb - 1) / hb;
    int beg = b * C, end = min(nnz, beg + C);
    for (int n = beg + tid; n < end; n += HT) {
        int u = ui[n], it = ii[n];
        float val = v[n];
        atomicAdd(&hA[u], val / log1pf(popraw[it] * rs0 + 1e-8f));
        int pU = atomicAdd(&curU[u], 1);
        pairsU[pU] = make_int2(it, __float_as_int(val));
        int pI = atomicAdd(&curI[it], 1);
        pairsI[pI] = make_int2(u, __float_as_int(val));
    }
    __syncthreads();
    float4* sA = (float4*)(sliceA + (size_t)b * NE);
    for (int j = tid; j < NE / 4; j += HT) sA[j] = hA4[j];
}

__global__ void k_actchunk(const float* __restrict__ sliceA, int spc, float* __restrict__ csA) {
    int i = blockIdx.x * 256 + threadIdx.x;
    int c = blockIdx.y;
    int b0 = c * spc;
    float a = 0.f;
    for (int b = b0; b < b0 + spc; ++b) a += sliceA[(size_t)b * NE + i];
    csA[(size_t)c * NE + i] = a;
}

__global__ void k_actfinal(const float* __restrict__ csA, float* act, float* normAcc) {
    __shared__ float red[4];
    int i = blockIdx.x * 256 + threadIdx.x;
    float a = 0.f;
    #pragma unroll
    for (int c = 0; c < NCH; ++c) a += csA[(size_t)c * NE + i];
    act[i] = a;
    float s = blockReduceSum(a * a, red);
    if (threadIdx.x == 0) atomicAdd(&normAcc[1], s);
}

// One row per 64-thread block (one wave). Level 1 sparse-scattered into
// lo1 (A) / hi1 (B); levels 2-3 dense. Interleaved batching: each lane
// handles groups {g0, g0+64, g0+128, g0+192} so every ds_read_b128 is
// stride-16B across lanes (conflict-free) AND 8 loads issue back-to-back (ILP).
__global__ __launch_bounds__(64) void k_rows(const int* __restrict__ ptr,
                                             const int2* __restrict__ pairs,
                                             const float* __restrict__ raw,
                                             const float* __restrict__ normAcc,
                                             int slot,
                                             float* __restrict__ w_out) {
    __shared__ __align__(16) float A[4112];  // lo1 at A[4+k], k<4098
    __shared__ __align__(16) float B[4112];  // hi1, then lo2 at B[4+k], k<2051
    int lane = threadIdx.x;
    int r = blockIdx.x;
    float4* A4 = (float4*)A;
    float4* B4 = (float4*)B;
    float2* B2 = (float2*)B;
    const float4 z4 = make_float4(0.f, 0.f, 0.f, 0.f);

    for (int j = lane; j < 1028; j += 64) { A4[j] = z4; B4[j] = z4; }
    __syncthreads();

    int beg = ptr[r], end = ptr[r + 1];
    for (int n = beg + lane; n < end; n += 64) {
        int2 pr = pairs[n];
        float v = __int_as_float(pr.y);
        int p = pr.x;
        int par = p & 1;
        int kb = (p >> 1) + 4;
        float l0 = par ? LO_R[5] : LO_R[4], l1 = par ? LO_R[3] : LO_R[2], l2 = par ? LO_R[1] : LO_R[0];
        float h0 = par ? HI_R[5] : HI_R[4], h1 = par ? HI_R[3] : HI_R[2], h2 = par ? HI_R[1] : HI_R[0];
        atomicAdd(&A[kb],     v * l0);
        atomicAdd(&A[kb + 1], v * l1);
        atomicAdd(&A[kb + 2], v * l2);
        atomicAdd(&B[kb],     v * h0);
        atomicAdd(&B[kb + 1], v * h1);
        atomicAdd(&B[kb + 2], v * h2);
    }
    __syncthreads();

    // s1 = ||hi1||^2 over all of B (pads zero): 16 independent stride-16B reads
    float s1 = 0.f;
    #pragma unroll
    for (int j = 0; j < 16; ++j) {
        float4 h = B4[j * 64 + lane];
        s1 += h.x * h.x + h.y * h.y + h.z * h.z + h.w * h.w;
    }
    if (lane < 4) {
        float4 h = B4[1024 + lane];
        s1 += h.x * h.x + h.y * h.y + h.z * h.z + h.w * h.w;
    }
    __syncthreads();  // all hi1 reads done before lo2 overwrites B

    // Level 2: A (lo1) -> B (lo2). 4 interleaved groups per lane per iter.
    float s2 = 0.f;
    #pragma unroll
    for (int blk = 0; blk < 4; ++blk) {
        int g0 = blk * 256 + lane;
        float4 a0 = A4[g0],       a0b = A4[g0 + 1];
        float4 a1 = A4[g0 + 64],  a1b = A4[g0 + 65];
        float4 a2 = A4[g0 + 128], a2b = A4[g0 + 129];
        float4 a3 = A4[g0 + 192], a3b = A4[g0 + 193];
        float lo0, hi0, lo1, hi1;
        conv_pair(a0, a0b, lo0, hi0, lo1, hi1);
        B2[2 + g0] = make_float2(lo0, lo1);
        s2 += hi0 * hi0 + hi1 * hi1;
        conv_pair(a1, a1b, lo0, hi0, lo1, hi1);
        B2[66 + g0] = make_float2(lo0, lo1);
        s2 += hi0 * hi0 + hi1 * hi1;
        conv_pair(a2, a2b, lo0, hi0, lo1, hi1);
        B2[130 + g0] = make_float2(lo0, lo1);
        s2 += hi0 * hi0 + hi1 * hi1;
        conv_pair(a3, a3b, lo0, hi0, lo1, hi1);
        B2[194 + g0] = make_float2(lo0, lo1);
        s2 += hi0 * hi0 + hi1 * hi1;
    }
    if (lane < 2) {  // tail groups g = 1024, 1025 -> k = 2048..2051
        int g = 1024 + lane;
        float4 a = A4[g], b = A4[g + 1];
        float lo0, hi0, lo1, hi1;
        conv_pair(a, b, lo0, hi0, lo1, hi1);
        B2[2 + g] = make_float2(lo0, lo1);
        s2 += hi0 * hi0 + hi1 * hi1;
    }
    if (lane >= 2 && lane < 4) B4[512 + lane] = z4;  // zero stale B[2056..2063]
    __syncthreads();

    // Level 3: B (lo2) -> registers. 514 groups; interleaved like level 2.
    float s3 = 0.f, ls = 0.f;
    #pragma unroll
    for (int blk = 0; blk < 2; ++blk) {
        int g0 = blk * 256 + lane;
        float4 b0 = B4[g0],       b0b = B4[g0 + 1];
        float4 b1 = B4[g0 + 64],  b1b = B4[g0 + 65];
        float4 b2 = B4[g0 + 128], b2b = B4[g0 + 129];
        float4 b3 = B4[g0 + 192], b3b = B4[g0 + 193];
        float lo0, hi0, lo1, hi1;
        conv_pair(b0, b0b, lo0, hi0, lo1, hi1);
        ls += lo0 + lo1; s3 += hi0 * hi0 + hi1 * hi1;
        conv_pair(b1, b1b, lo0, hi0, lo1, hi1);
        ls += lo0 + lo1; s3 += hi0 * hi0 + hi1 * hi1;
        conv_pair(b2, b2b, lo0, hi0, lo1, hi1);
        ls += lo0 + lo1; s3 += hi0 * hi0 + hi1 * hi1;
        conv_pair(b3, b3b, lo0, hi0, lo1, hi1);
        ls += lo0 + lo1; s3 += hi0 * hi0 + hi1 * hi1;
    }
    if (lane < 2) {  // tail groups g = 512, 513
        int g = 512 + lane;
        float4 a = B4[g], b = B4[g + 1];
        float lo0, hi0, lo1, hi1;
        conv_pair(a, b, lo0, hi0, lo1, hi1);
        ls += lo0 + lo1;
        s3 += hi0 * hi0 + hi1 * hi1;
    }

    #pragma unroll
    for (int off = 32; off > 0; off >>= 1) {
        s1 += __shfl_down(s1, off);
        s2 += __shfl_down(s2, off);
        s3 += __shfl_down(s3, off);
        ls += __shfl_down(ls, off);
    }
    if (lane == 0) {
        float rs = 1.f / (sqrtf(normAcc[slot]) + 1e-8f);
        float sc = 1.f + raw[r] * rs;
        float high = (sqrtf(s1) + sqrtf(s2) + sqrtf(s3)) * sc;
        float low = ls * (1.f / 1028.f) * sc;
        float a1 = fmaxf(low, 1e-6f);
        float a2 = fmaxf(high, 1e-6f);
        w_out[r] = a1 / (a1 + a2);
    }
}

__global__ void k_out(const int* __restrict__ ui, const int* __restrict__ ii,
                      const float* __restrict__ v, int nnz,
                      const float* __restrict__ u_w, const float* __restrict__ i_w,
                      float* __restrict__ out) {
    int idx = blockIdx.x * blockDim.x + threadIdx.x;
    int stride = gridDim.x * blockDim.x;
    for (int n = idx; n < nnz; n += stride) {
        float val = v[n];
        float wu = u_w[ui[n]], wi = i_w[ii[n]];
        float wun = 1.f - wu, win = 1.f - wi;
        out[n] = val * wu * wi;
        out[(size_t)nnz + n] = val * wun * win;
        out[2 * (size_t)nnz + n] = val * wu * win;
        out[3 * (size_t)nnz + n] = val * wun * wi;
    }
}

extern "C" void kernel_launch(void* const* d_in, const int* in_sizes, int n_in,
                              void* d_out, int out_size, void* d_ws, size_t ws_size,
                              hipStream_t stream) {
    const int* ui = (const int*)d_in[0];
    const int* ii = (const int*)d_in[1];
    const float* vals = (const float*)d_in[2];
    int nnz = in_sizes[0];
    float* out = (float*)d_out;

    char* ws = (char*)d_ws;
    size_t off = 0;
    auto take = [&](size_t bytes) -> char* {
        char* p = ws + off;
        off = (off + bytes + 255) & ~(size_t)255;
        return p;
    };

    int*   cntU    = (int*)take(NE * 4);
    int*   cntI    = (int*)take(NE * 4);
    float* popraw  = (float*)take(NE * 4);
    float* actraw  = (float*)take(NE * 4);
    int*   ptrU    = (int*)take((NE + 1) * 4);
    int*   ptrI    = (int*)take((NE + 1) * 4);
    float* u_w     = (float*)take(NE * 4);
    float* i_w     = (float*)take(NE * 4);
    float* normAcc = (float*)take(256);
    int*   csU     = (int*)take((size_t)NCH * NE * 4);
    int*   csI     = (int*)take((size_t)NCH * NE * 4);
    float* csS     = (float*)take((size_t)NCH * NE * 4);  // reused as csA
    int2*  pairsU  = (int2*)take((size_t)nnz * 8);
    int2*  pairsI  = (int2*)take((size_t)nnz * 8);
    size_t fixedEnd = off;

    int hb = 256;
    while (hb > 8 && fixedEnd + 3 * (size_t)hb * NE * 4 + 4096 > ws_size) hb >>= 1;
    int spc = hb / NCH;
    int*   sliceU = (int*)take((size_t)hb * NE * 4);
    int*   sliceI = (int*)take((size_t)hb * NE * 4);
    float* sliceS = (float*)take((size_t)hb * NE * 4);  // reused as sliceA

    hipMemsetAsync(normAcc, 0, 256, stream);

    int nb = (nnz + 255) / 256;
    if (nb > 2048) nb = 2048;

    // popularity + counts
    k_hist3<<<hb, HT, 0, stream>>>(ui, ii, vals, nnz, sliceU, sliceI, sliceS);
    k_chunksum3<<<dim3(32, NCH), 256, 0, stream>>>(sliceU, sliceI, sliceS, spc, csU, csI, csS);
    k_final3<<<32, 256, 0, stream>>>(csU, csI, csS, cntU, cntI, popraw, normAcc);

    // counting-sort offsets for both tables
    k_scan2<<<2, 256, 0, stream>>>(cntU, cntI, ptrU, ptrI);
    k_colscanB<<<dim3(32, 2), 256, 0, stream>>>(csU, csI, ptrU, ptrI);
    k_colscanC<<<dim3(32, NCH, 2), 256, 0, stream>>>(sliceU, sliceI, csU, csI, spc);

    // one fused pass: both scatters + activity histogram partials
    k_scatter2<<<hb, HT, 0, stream>>>(ui, ii, vals, nnz, sliceU, sliceI,
                                      popraw, normAcc, pairsU, pairsI, sliceS);

    // item rows (needs pairsI + popraw + normAcc[0])
    k_rows<<<NE, 64, 0, stream>>>(ptrI, pairsI, popraw, normAcc, 0, i_w);

    // finish activity, then user rows
    k_actchunk<<<dim3(32, NCH), 256, 0, stream>>>(sliceS, spc, csS);
    k_actfinal<<<32, 256, 0, stream>>>(csS, actraw, normAcc);
    k_rows<<<NE, 64, 0, stream>>>(ptrU, pairsU, actraw, normAcc, 1, u_w);

    k_out<<<nb, 256, 0, stream>>>(ui, ii, vals, nnz, u_w, i_w, out);
}

// Round 7
// 326.040 us; speedup vs baseline: 2.5830x; 1.0424x over previous
//
#include <hip/hip_runtime.h>
#include <math.h>

#define NE 8192   // num_users == num_items
#define HT 1024   // histogram/scatter block threads
#define NCH 8     // slice chunks for two-level colscan/reduce
#define RT 256    // k_rows threads (4 waves) per row

// db3 analysis filters, reversed (cross-correlation of reversed filter == convolution)
__device__ __constant__ float LO_R[6] = {
    0.3326705529509569f, 0.8068915093133388f, 0.4598775021193313f,
    -0.13501102001039084f, -0.08544127388224149f, 0.035226291882100656f};
__device__ __constant__ float HI_R[6] = {
    0.035226291882100656f, 0.08544127388224149f, -0.13501102001039084f,
    -0.4598775021193313f, 0.8068915093133388f, -0.3326705529509569f};

// 256-thread block reduce; valid on thread 0.
__device__ __forceinline__ float blockReduceSum(float v, float* red) {
    #pragma unroll
    for (int off = 32; off > 0; off >>= 1) v += __shfl_down(v, off);
    int lane = threadIdx.x & 63, wid = threadIdx.x >> 6;
    if (lane == 0) red[wid] = v;
    __syncthreads();
    float r = 0.f;
    if (threadIdx.x == 0) {
        int nw = blockDim.x >> 6;
        for (int i = 0; i < nw; ++i) r += red[i];
    }
    return r;
}

// 4-value fused block reduce; valid on thread 0.
__device__ __forceinline__ float4 blockReduce4(float a, float b, float c, float d,
                                               float (*red)[4]) {
    #pragma unroll
    for (int off = 32; off > 0; off >>= 1) {
        a += __shfl_down(a, off); b += __shfl_down(b, off);
        c += __shfl_down(c, off); d += __shfl_down(d, off);
    }
    int lane = threadIdx.x & 63, wid = threadIdx.x >> 6;
    if (lane == 0) { red[wid][0] = a; red[wid][1] = b; red[wid][2] = c; red[wid][3] = d; }
    __syncthreads();
    float4 r = make_float4(0.f, 0.f, 0.f, 0.f);
    if (threadIdx.x == 0) {
        int nw = blockDim.x >> 6;
        for (int w = 0; w < nw; ++w) {
            r.x += red[w][0]; r.y += red[w][1]; r.z += red[w][2]; r.w += red[w][3];
        }
    }
    return r;
}

// (lo,hi) output pair k=2g, 2g+1 from padded input groups a=X4[g], b=X4[g+1]
__device__ __forceinline__ void conv_pair(float4 a, float4 b,
                                          float& lo0, float& hi0,
                                          float& lo1, float& hi1) {
    lo0 = a.x * LO_R[0]; hi0 = a.x * HI_R[0];
    lo0 = fmaf(a.y, LO_R[1], lo0); hi0 = fmaf(a.y, HI_R[1], hi0);
    lo0 = fmaf(a.z, LO_R[2], lo0); hi0 = fmaf(a.z, HI_R[2], hi0);
    lo0 = fmaf(a.w, LO_R[3], lo0); hi0 = fmaf(a.w, HI_R[3], hi0);
    lo0 = fmaf(b.x, LO_R[4], lo0); hi0 = fmaf(b.x, HI_R[4], hi0);
    lo0 = fmaf(b.y, LO_R[5], lo0); hi0 = fmaf(b.y, HI_R[5], hi0);
    lo1 = a.z * LO_R[0]; hi1 = a.z * HI_R[0];
    lo1 = fmaf(a.w, LO_R[1], lo1); hi1 = fmaf(a.w, HI_R[1], hi1);
    lo1 = fmaf(b.x, LO_R[2], lo1); hi1 = fmaf(b.x, HI_R[2], hi1);
    lo1 = fmaf(b.y, LO_R[3], lo1); hi1 = fmaf(b.y, HI_R[3], hi1);
    lo1 = fmaf(b.z, LO_R[4], lo1); hi1 = fmaf(b.z, HI_R[4], hi1);
    lo1 = fmaf(b.w, LO_R[5], lo1); hi1 = fmaf(b.w, HI_R[5], hi1);
}

__global__ __launch_bounds__(HT) void k_hist3(const int* __restrict__ ui,
                                              const int* __restrict__ ii,
                                              const float* __restrict__ v, int nnz,
                                              int* __restrict__ sliceU,
                                              int* __restrict__ sliceI,
                                              float* __restrict__ sliceS) {
    __shared__ int hU[NE];
    __shared__ int hI[NE];
    __shared__ float hS[NE];
    int b = blockIdx.x, tid = threadIdx.x, hb = gridDim.x;
    int4* hU4 = (int4*)hU; int4* hI4 = (int4*)hI; int4* hS4 = (int4*)hS;
    int4 z4 = make_int4(0, 0, 0, 0);
    for (int j = tid; j < NE / 4; j += HT) { hU4[j] = z4; hI4[j] = z4; hS4[j] = z4; }
    __syncthreads();
    int C = (nnz + hb - 1) / hb;
    int beg = b * C, end = min(nnz, beg + C);
    for (int n = beg + tid; n < end; n += HT) {
        atomicAdd(&hU[ui[n]], 1);
        int it = ii[n];
        atomicAdd(&hI[it], 1);
        atomicAdd(&hS[it], v[n]);
    }
    __syncthreads();
    size_t base = (size_t)b * NE;
    int4* sU = (int4*)(sliceU + base); int4* sI = (int4*)(sliceI + base);
    int4* sS = (int4*)(sliceS + base);
    for (int j = tid; j < NE / 4; j += HT) { sU[j] = hU4[j]; sI[j] = hI4[j]; sS[j] = hS4[j]; }
}

__global__ void k_chunksum3(const int* __restrict__ sliceU, const int* __restrict__ sliceI,
                            const float* __restrict__ sliceS, int spc,
                            int* __restrict__ csU, int* __restrict__ csI,
                            float* __restrict__ csS) {
    int i = blockIdx.x * 256 + threadIdx.x;
    int c = blockIdx.y;
    int b0 = c * spc;
    int cu = 0, ci = 0; float sv = 0.f;
    for (int b = b0; b < b0 + spc; ++b) {
        size_t o = (size_t)b * NE + i;
        cu += sliceU[o]; ci += sliceI[o]; sv += sliceS[o];
    }
    size_t oc = (size_t)c * NE + i;
    csU[oc] = cu; csI[oc] = ci; csS[oc] = sv;
}

__global__ void k_final3(const int* __restrict__ csU, const int* __restrict__ csI,
                         const float* __restrict__ csS,
                         int* cntU, int* cntI, float* popraw, float* normAcc) {
    __shared__ float red[4];
    int i = blockIdx.x * 256 + threadIdx.x;
    int cu = 0, ci = 0; float sv = 0.f;
    #pragma unroll
    for (int c = 0; c < NCH; ++c) {
        size_t o = (size_t)c * NE + i;
        cu += csU[o]; ci += csI[o]; sv += csS[o];
    }
    cntU[i] = cu; cntI[i] = ci;
    float p = log1pf((float)ci) * sv;
    popraw[i] = p;
    float s = blockReduceSum(p * p, red);
    if (threadIdx.x == 0) atomicAdd(&normAcc[0], s);
}

__global__ void k_scan2(const int* __restrict__ cntU, const int* __restrict__ cntI,
                        int* ptrU, int* ptrI) {
    __shared__ int sums[256];
    const int* cnt = blockIdx.x ? cntI : cntU;
    int* ptr = blockIdx.x ? ptrI : ptrU;
    int tid = threadIdx.x;
    int base = tid * 32;
    int local[32];
    int s = 0;
    #pragma unroll
    for (int j = 0; j < 32; ++j) { local[j] = cnt[base + j]; s += local[j]; }
    sums[tid] = s;
    __syncthreads();
    for (int off = 1; off < 256; off <<= 1) {
        int t = (tid >= off) ? sums[tid - off] : 0;
        __syncthreads();
        sums[tid] += t;
        __syncthreads();
    }
    int run = (tid > 0) ? sums[tid - 1] : 0;
    #pragma unroll
    for (int j = 0; j < 32; ++j) { ptr[base + j] = run; run += local[j]; }
    if (tid == 255) ptr[NE] = run;
}

__global__ void k_colscanB(int* csU, int* csI,
                           const int* __restrict__ ptrU, const int* __restrict__ ptrI) {
    int i = blockIdx.x * 256 + threadIdx.x;
    int* cs = blockIdx.y ? csI : csU;
    const int* ptr = blockIdx.y ? ptrI : ptrU;
    int run = ptr[i];
    #pragma unroll
    for (int c = 0; c < NCH; ++c) {
        size_t o = (size_t)c * NE + i;
        int t = cs[o]; cs[o] = run; run += t;
    }
}

__global__ void k_colscanC(int* sliceU, int* sliceI,
                           const int* __restrict__ csU, const int* __restrict__ csI, int spc) {
    int i = blockIdx.x * 256 + threadIdx.x;
    int c = blockIdx.y;
    int* slice = blockIdx.z ? sliceI : sliceU;
    const int* cs = blockIdx.z ? csI : csU;
    int run = cs[(size_t)c * NE + i];
    int b0 = c * spc;
    for (int b = b0; b < b0 + spc; ++b) {
        size_t o = (size_t)b * NE + i;
        int t = slice[o]; slice[o] = run; run += t;
    }
}

// Fused: both counting-sort scatters + user-activity histogram (one nnz pass).
__global__ __launch_bounds__(HT) void k_scatter2(const int* __restrict__ ui,
                                                 const int* __restrict__ ii,
                                                 const float* __restrict__ v, int nnz,
                                                 const int* __restrict__ sliceU,
                                                 const int* __restrict__ sliceI,
                                                 const float* __restrict__ popraw,
                                                 const float* __restrict__ normAcc,
                                                 int2* __restrict__ pairsU,
                                                 int2* __restrict__ pairsI,
                                                 float* __restrict__ sliceA) {
    __shared__ int curU[NE];
    __shared__ int curI[NE];
    __shared__ float hA[NE];
    int b = blockIdx.x, tid = threadIdx.x, hb = gridDim.x;
    const int4* sU = (const int4*)(sliceU + (size_t)b * NE);
    const int4* sI = (const int4*)(sliceI + (size_t)b * NE);
    int4* cU4 = (int4*)curU; int4* cI4 = (int4*)curI;
    float4* hA4 = (float4*)hA;
    float4 zf = make_float4(0.f, 0.f, 0.f, 0.f);
    for (int j = tid; j < NE / 4; j += HT) { cU4[j] = sU[j]; cI4[j] = sI[j]; hA4[j] = zf; }
    __syncthreads();
    float rs0 = 1.f / (sqrtf(normAcc[0]) + 1e-8f);
    int C = (nnz + hb - 1) / hb;
    int beg = b * C, end = min(nnz, beg + C);
    for (int n = beg + tid; n < end; n += HT) {
        int u = ui[n], it = ii[n];
        float val = v[n];
        atomicAdd(&hA[u], val / log1pf(popraw[it] * rs0 + 1e-8f));
        int pU = atomicAdd(&curU[u], 1);
        pairsU[pU] = make_int2(it, __float_as_int(val));
        int pI = atomicAdd(&curI[it], 1);
        pairsI[pI] = make_int2(u, __float_as_int(val));
    }
    __syncthreads();
    float4* sA = (float4*)(sliceA + (size_t)b * NE);
    for (int j = tid; j < NE / 4; j += HT) sA[j] = hA4[j];
}

__global__ void k_actchunk(const float* __restrict__ sliceA, int spc, float* __restrict__ csA) {
    int i = blockIdx.x * 256 + threadIdx.x;
    int c = blockIdx.y;
    int b0 = c * spc;
    float a = 0.f;
    for (int b = b0; b < b0 + spc; ++b) a += sliceA[(size_t)b * NE + i];
    csA[(size_t)c * NE + i] = a;
}

__global__ void k_actfinal(const float* __restrict__ csA, float* act, float* normAcc) {
    __shared__ float red[4];
    int i = blockIdx.x * 256 + threadIdx.x;
    float a = 0.f;
    #pragma unroll
    for (int c = 0; c < NCH; ++c) a += csA[(size_t)c * NE + i];
    act[i] = a;
    float s = blockReduceSum(a * a, red);
    if (threadIdx.x == 0) atomicAdd(&normAcc[1], s);
}

// One row per 256-thread block (4 waves). 33 KB LDS/row -> 4 blocks/CU
// = 16 waves/CU = 4 waves/SIMD: TLP hides LDS latency (the round-4/5/6
// 1-wave/SIMD variants were latency-exposed at ~102-109 us; round-2's
// 3-waves/SIMD was 79 us despite 2x the VALU work). Level 1 sparse-scattered
// into lo1 (A) / hi1 (B); levels 2-3 dense, stride-16B reads (conflict-free).
__global__ __launch_bounds__(RT) void k_rows(const int* __restrict__ ptr,
                                             const int2* __restrict__ pairs,
                                             const float* __restrict__ raw,
                                             const float* __restrict__ normAcc,
                                             int slot,
                                             float* __restrict__ w_out) {
    __shared__ __align__(16) float A[4112];  // lo1 at A[4+k], k<4098
    __shared__ __align__(16) float B[4112];  // hi1, then lo2 at B[4+k], k<2051
    __shared__ float red[RT / 64][4];
    int tid = threadIdx.x;
    int r = blockIdx.x;
    float4* A4 = (float4*)A;
    float4* B4 = (float4*)B;
    float2* B2 = (float2*)B;
    const float4 z4 = make_float4(0.f, 0.f, 0.f, 0.f);

    for (int j = tid; j < 1028; j += RT) { A4[j] = z4; B4[j] = z4; }
    __syncthreads();

    int beg = ptr[r], end = ptr[r + 1];
    for (int n = beg + tid; n < end; n += RT) {
        int2 pr = pairs[n];
        float v = __int_as_float(pr.y);
        int p = pr.x;
        int par = p & 1;
        int kb = (p >> 1) + 4;
        float l0 = par ? LO_R[5] : LO_R[4], l1 = par ? LO_R[3] : LO_R[2], l2 = par ? LO_R[1] : LO_R[0];
        float h0 = par ? HI_R[5] : HI_R[4], h1 = par ? HI_R[3] : HI_R[2], h2 = par ? HI_R[1] : HI_R[0];
        atomicAdd(&A[kb],     v * l0);
        atomicAdd(&A[kb + 1], v * l1);
        atomicAdd(&A[kb + 2], v * l2);
        atomicAdd(&B[kb],     v * h0);
        atomicAdd(&B[kb + 1], v * h1);
        atomicAdd(&B[kb + 2], v * h2);
    }
    __syncthreads();

    // s1 = ||hi1||^2 over all of B (pads zero); stride-16B reads, conflict-free
    float s1 = 0.f;
    for (int j = tid; j < 1028; j += RT) {
        float4 h = B4[j];
        s1 += h.x * h.x + h.y * h.y + h.z * h.z + h.w * h.w;
    }
    __syncthreads();  // all hi1 reads done before lo2 overwrites B

    // Level 2: A (lo1, N=4098) -> B (lo2, 2051); hi2 norm in registers.
    // g=1025 produces (valid k=2050, k=2051 from zero pad) - safe.
    float s2 = 0.f;
    for (int g = tid; g < 1026; g += RT) {
        float4 a = A4[g], b = A4[g + 1];
        float lo0, hi0, lo1, hi1;
        conv_pair(a, b, lo0, hi0, lo1, hi1);
        B2[2 + g] = make_float2(lo0, lo1);
        s2 += hi0 * hi0 + hi1 * hi1;
    }
    if (tid >= 2 && tid < 4) B4[512 + tid] = z4;  // zero stale hi1 floats 2056..2063
    __syncthreads();

    // Level 3: B (lo2, N=2051) -> registers (1028 outputs = 514 group-pairs)
    float s3 = 0.f, ls = 0.f;
    for (int g = tid; g < 514; g += RT) {
        float4 a = B4[g], b = B4[g + 1];
        float lo0, hi0, lo1, hi1;
        conv_pair(a, b, lo0, hi0, lo1, hi1);
        ls += lo0 + lo1;
        s3 += hi0 * hi0 + hi1 * hi1;
    }

    float4 t = blockReduce4(s1, s2, s3, ls, red);
    if (tid == 0) {
        float rs = 1.f / (sqrtf(normAcc[slot]) + 1e-8f);
        float sc = 1.f + raw[r] * rs;
        float high = (sqrtf(t.x) + sqrtf(t.y) + sqrtf(t.z)) * sc;
        float low = t.w * (1.f / 1028.f) * sc;
        float a1 = fmaxf(low, 1e-6f);
        float a2 = fmaxf(high, 1e-6f);
        w_out[r] = a1 / (a1 + a2);
    }
}

__global__ void k_out(const int* __restrict__ ui, const int* __restrict__ ii,
                      const float* __restrict__ v, int nnz,
                      const float* __restrict__ u_w, const float* __restrict__ i_w,
                      float* __restrict__ out) {
    int idx = blockIdx.x * blockDim.x + threadIdx.x;
    int stride = gridDim.x * blockDim.x;
    for (int n = idx; n < nnz; n += stride) {
        float val = v[n];
        float wu = u_w[ui[n]], wi = i_w[ii[n]];
        float wun = 1.f - wu, win = 1.f - wi;
        out[n] = val * wu * wi;
        out[(size_t)nnz + n] = val * wun * win;
        out[2 * (size_t)nnz + n] = val * wu * win;
        out[3 * (size_t)nnz + n] = val * wun * wi;
    }
}

extern "C" void kernel_launch(void* const* d_in, const int* in_sizes, int n_in,
                              void* d_out, int out_size, void* d_ws, size_t ws_size,
                              hipStream_t stream) {
    const int* ui = (const int*)d_in[0];
    const int* ii = (const int*)d_in[1];
    const float* vals = (const float*)d_in[2];
    int nnz = in_sizes[0];
    float* out = (float*)d_out;

    char* ws = (char*)d_ws;
    size_t off = 0;
    auto take = [&](size_t bytes) -> char* {
        char* p = ws + off;
        off = (off + bytes + 255) & ~(size_t)255;
        return p;
    };

    int*   cntU    = (int*)take(NE * 4);
    int*   cntI    = (int*)take(NE * 4);
    float* popraw  = (float*)take(NE * 4);
    float* actraw  = (float*)take(NE * 4);
    int*   ptrU    = (int*)take((NE + 1) * 4);
    int*   ptrI    = (int*)take((NE + 1) * 4);
    float* u_w     = (float*)take(NE * 4);
    float* i_w     = (float*)take(NE * 4);
    float* normAcc = (float*)take(256);
    int*   csU     = (int*)take((size_t)NCH * NE * 4);
    int*   csI     = (int*)take((size_t)NCH * NE * 4);
    float* csS     = (float*)take((size_t)NCH * NE * 4);  // reused as csA
    int2*  pairsU  = (int2*)take((size_t)nnz * 8);
    int2*  pairsI  = (int2*)take((size_t)nnz * 8);
    size_t fixedEnd = off;

    int hb = 256;
    while (hb > 8 && fixedEnd + 3 * (size_t)hb * NE * 4 + 4096 > ws_size) hb >>= 1;
    int spc = hb / NCH;
    int*   sliceU = (int*)take((size_t)hb * NE * 4);
    int*   sliceI = (int*)take((size_t)hb * NE * 4);
    float* sliceS = (float*)take((size_t)hb * NE * 4);  // reused as sliceA

    hipMemsetAsync(normAcc, 0, 256, stream);

    int nb = (nnz + 255) / 256;
    if (nb > 2048) nb = 2048;

    // popularity + counts
    k_hist3<<<hb, HT, 0, stream>>>(ui, ii, vals, nnz, sliceU, sliceI, sliceS);
    k_chunksum3<<<dim3(32, NCH), 256, 0, stream>>>(sliceU, sliceI, sliceS, spc, csU, csI, csS);
    k_final3<<<32, 256, 0, stream>>>(csU, csI, csS, cntU, cntI, popraw, normAcc);

    // counting-sort offsets for both tables
    k_scan2<<<2, 256, 0, stream>>>(cntU, cntI, ptrU, ptrI);
    k_colscanB<<<dim3(32, 2), 256, 0, stream>>>(csU, csI, ptrU, ptrI);
    k_colscanC<<<dim3(32, NCH, 2), 256, 0, stream>>>(sliceU, sliceI, csU, csI, spc);

    // one fused pass: both scatters + activity histogram partials
    k_scatter2<<<hb, HT, 0, stream>>>(ui, ii, vals, nnz, sliceU, sliceI,
                                      popraw, normAcc, pairsU, pairsI, sliceS);

    // item rows (needs pairsI + popraw + normAcc[0])
    k_rows<<<NE, RT, 0, stream>>>(ptrI, pairsI, popraw, normAcc, 0, i_w);

    // finish activity, then user rows
    k_actchunk<<<dim3(32, NCH), 256, 0, stream>>>(sliceS, spc, csS);
    k_actfinal<<<32, 256, 0, stream>>>(csS, actraw, normAcc);
    k_rows<<<NE, RT, 0, stream>>>(ptrU, pairsU, actraw, normAcc, 1, u_w);

    k_out<<<nb, 256, 0, stream>>>(ui, ii, vals, nnz, u_w, i_w, out);
}